// Round 2
// baseline (1185.113 us; speedup 1.0000x reference)
//
#include <hip/hip_runtime.h>
#include <stdint.h>

// Net_18021682774696 — MTGNN-ish: 3x { TCN(2 gated units) ; skip ; 3x mixprop ; LN+ReLU } + end convs.
// Round 2: runtime input-dtype detection (fp32 vs bf16) + canonicalize all float
// inputs to internal bf16 buffers; compute pipeline identical to round 1.

typedef uint16_t u16;
typedef uint32_t u32;
typedef __attribute__((ext_vector_type(8))) short s8v;
typedef __attribute__((ext_vector_type(4))) float f4v;

#define MFMA16(a,b,c) __builtin_amdgcn_mfma_f32_16x16x32_bf16(a,b,c,0,0,0)

__device__ __forceinline__ float b2f(u16 u){ union{u32 i; float f;} x; x.i=(u32)u<<16; return x.f; }
__device__ __forceinline__ u16 f2b(float f){
  u32 u = __builtin_bit_cast(u32, f);
  u32 r = (u + 0x7fffu + ((u >> 16) & 1u)) >> 16;   // RNE
  return (u16)r;
}

// ---------------------------------------------------------------------------
// kdetect: decide whether float inputs are fp32 (flag=1) or bf16 (flag=0).
// Scans first 65536 u16 of x for bf16 Inf/NaN bit patterns (exponent 0xFF).
// bf16 normal data: zero hits. fp32 data read as u16: low halves are random
// mantissa bits -> ~128 expected hits. Deterministic per fixed input.
// ---------------------------------------------------------------------------
__global__ __launch_bounds__(256) void kdetect(const u16* __restrict__ x, int* __restrict__ flag)
{
  const int i = threadIdx.x;
  int cnt = 0;
  for (int k = i; k < 65536; k += 256) {
    const u16 v = x[k];
    if ((v & 0x7F80u) == 0x7F80u) cnt++;
  }
  __shared__ int s[256];
  s[i] = cnt; __syncthreads();
  for (int st = 128; st; st >>= 1) { if (i < st) s[i] += s[i+st]; __syncthreads(); }
  if (i == 0) flag[0] = (s[0] > 0) ? 1 : 0;
}

// kcvt4: canonicalize one input array into bf16 (4 elements/thread).
__global__ __launch_bounds__(256) void kcvt4(const void* __restrict__ src, u16* __restrict__ dst,
                                             int n4, const int* __restrict__ flag)
{
  const int i = blockIdx.x*256 + threadIdx.x;
  if (i >= n4) return;
  if (*flag) {
    const float4 v = ((const float4*)src)[i];
    u16 o[4]; o[0]=f2b(v.x); o[1]=f2b(v.y); o[2]=f2b(v.z); o[3]=f2b(v.w);
    *(uint2*)(dst + (long)i*4) = *(uint2*)o;
  } else {
    *(uint2*)(dst + (long)i*4) = ((const uint2*)src)[i];
  }
}

// ---------------------------------------------------------------------------
// kprop: C[v, c] = sum_k A'[v,k] * X[c,k]   (A' = A or A^T, staged via LDS)
//   MODE 0: out = (acc + diag[c][v]) * rinv[v]  -> bf16 (mixprop propagation)
//   MODE 1: out = acc + bias[c] + diag[c][v]    -> f32  (combine + residual)
// ---------------------------------------------------------------------------
template<int TRANSA, int MODE>
__global__ __launch_bounds__(256) void kprop(
    const u16* __restrict__ A, long a_bs, int lda, int K,
    const u16* __restrict__ X, long x_bs, int ldx,
    const u16* __restrict__ D, long d_bs,
    const float* __restrict__ rinv, long r_bs,
    const float* __restrict__ bias,
    u16* __restrict__ out0, float* __restrict__ out1, long o_bs)
{
  __shared__ u16 As[4][2][16][40];
  __shared__ f4v red[4][2][64];
  const int tid = threadIdx.x;
  const int wave = tid >> 6, lane = tid & 63;
  const int lw = lane & 15, quad = lane >> 4;
  const int v0 = blockIdx.x * 16;
  const int ball = blockIdx.z + blockIdx.y;
  const u16* Ab = A + (long)ball * a_bs;
  const u16* Xb = X + (long)ball * x_bs;
  const int KC = K >> 5;

  f4v acc0 = {0.f,0.f,0.f,0.f}, acc1 = {0.f,0.f,0.f,0.f};

  int r0, c0_;
  if (TRANSA == 0) { r0 = lane >> 2; c0_ = (lane & 3) * 8; }   // 16 rows x 32 k
  else             { r0 = lane >> 1; c0_ = (lane & 1) * 8; }   // 32 k-rows x 16 v

  int ci = wave;
  bool has = ci < KC;
  uint4 d = make_uint4(0,0,0,0);
  if (has) {
    d = (TRANSA == 0)
      ? *(const uint4*)(Ab + (long)(v0 + r0) * lda + ci * 32 + c0_)
      : *(const uint4*)(Ab + (long)(ci * 32 + r0) * lda + v0 + c0_);
  }
  int buf = 0;
  while (has) {
    if (TRANSA == 0) {
      *(uint4*)&As[wave][buf][r0][c0_] = d;
    } else {
      u16 tmp[8]; *(uint4*)tmp = d;
      #pragma unroll
      for (int e = 0; e < 8; e++) As[wave][buf][c0_ + e][r0] = tmp[e];
    }
    const int cn = ci + 4;
    const bool hn = cn < KC;
    if (hn) {
      d = (TRANSA == 0)
        ? *(const uint4*)(Ab + (long)(v0 + r0) * lda + cn * 32 + c0_)
        : *(const uint4*)(Ab + (long)(cn * 32 + r0) * lda + v0 + c0_);
    }
    s8v af = *(const s8v*)&As[wave][buf][lw][quad * 8];
    const u16* xk = Xb + ci * 32 + quad * 8;
    s8v b0 = *(const s8v*)(xk + (long)lw * ldx);
    s8v b1 = *(const s8v*)(xk + (long)(16 + lw) * ldx);
    acc0 = MFMA16(af, b0, acc0);
    acc1 = MFMA16(af, b1, acc1);
    ci = cn; has = hn; buf ^= 1;
  }
  red[wave][0][lane] = acc0;
  red[wave][1][lane] = acc1;
  __syncthreads();
  if (wave == 0) {
    const int vb = v0 + quad * 4;
    #pragma unroll
    for (int nt = 0; nt < 2; nt++) {
      f4v a = red[0][nt][lane] + red[1][nt][lane] + red[2][nt][lane] + red[3][nt][lane];
      const int c = nt * 16 + lw;
      const u16* dp = D + (long)ball * d_bs + (long)c * 2048 + vb;
      if (MODE == 0) {
        const float* rp = rinv + (long)ball * r_bs + vb;
        u16 pk[4];
        #pragma unroll
        for (int r = 0; r < 4; r++) pk[r] = f2b((a[r] + b2f(dp[r])) * rp[r]);
        *(uint2*)(out0 + (long)ball * o_bs + (long)c * 2048 + vb) = *(uint2*)pk;
      } else {
        const float bs = bias[c];
        float4 st;
        st.x = a[0] + bs + b2f(dp[0]);
        st.y = a[1] + bs + b2f(dp[1]);
        st.z = a[2] + bs + b2f(dp[2]);
        st.w = a[3] + bs + b2f(dp[3]);
        *(float4*)(out1 + (long)ball * o_bs + (long)c * 2048 + vb) = st;
      }
    }
  }
}

// ---------------------------------------------------------------------------
// ktcn: gated TCN unit.  out[j,o] = tanh(H@Wf^T + bf) * sigmoid(H@Wg^T + bg)
// ---------------------------------------------------------------------------
__global__ __launch_bounds__(256) void ktcn(
    const u16* __restrict__ H, const u16* __restrict__ Wf, const u16* __restrict__ bfv,
    const u16* __restrict__ Wg, const u16* __restrict__ bgv, u16* __restrict__ out)
{
  __shared__ u16 As[64][40];
  const int tid = threadIdx.x, wave = tid>>6, lane = tid&63, lw = lane&15, quad = lane>>4;
  const long j0 = (long)blockIdx.x * 64;
  const f4v zero = {0.f,0.f,0.f,0.f};
  f4v accf[8], accg[8];
  #pragma unroll
  for (int nt=0; nt<8; nt++){ accf[nt] = zero; accg[nt] = zero; }
  const int r = tid>>2, kk = (tid&3)*8;
  for (int k0 = 0; k0 < 128; k0 += 32) {
    *(uint4*)&As[r][kk] = *(const uint4*)(H + (j0 + r)*128 + k0 + kk);
    __syncthreads();
    s8v a = *(const s8v*)&As[wave*16 + lw][quad*8];
    #pragma unroll
    for (int nt = 0; nt < 8; nt++) {
      const int o = nt*16 + lw;
      s8v bf_ = *(const s8v*)(Wf + o*128 + k0 + quad*8);
      s8v bg_ = *(const s8v*)(Wg + o*128 + k0 + quad*8);
      accf[nt] = MFMA16(a, bf_, accf[nt]);
      accg[nt] = MFMA16(a, bg_, accg[nt]);
    }
    __syncthreads();
  }
  #pragma unroll
  for (int nt = 0; nt < 8; nt++) {
    const int o = nt*16 + lw;
    const float fb = b2f(bfv[o]), gb = b2f(bgv[o]);
    #pragma unroll
    for (int rr = 0; rr < 4; rr++) {
      const long j = j0 + wave*16 + quad*4 + rr;
      const float f = accf[nt][rr] + fb, g = accg[nt][rr] + gb;
      const float e2 = __expf(2.f*f);
      const float th = 1.f - 2.f/(e2 + 1.f);
      const float sg = 1.f/(1.f + __expf(-g));
      out[j*128 + o] = f2b(th*sg);
    }
  }
}

// ---------------------------------------------------------------------------
// kskip: C[j,o] = A@W^T + bias (+ prev skip).  N=256 fixed.
// ---------------------------------------------------------------------------
__global__ __launch_bounds__(256) void kskip(
    const u16* __restrict__ A, int lda, int K,
    const u16* __restrict__ W, int ldb,
    const u16* __restrict__ bias,
    float* __restrict__ skipbuf, int addprev, int mode, u16* __restrict__ outb)
{
  __shared__ u16 As[64][40];
  const int tid = threadIdx.x, wave = tid>>6, lane = tid&63, lw = lane&15, quad = lane>>4;
  const long j0 = (long)blockIdx.x * 64;
  const f4v zero = {0.f,0.f,0.f,0.f};
  f4v acc[16];
  #pragma unroll
  for (int nt=0; nt<16; nt++) acc[nt] = zero;
  const int r = tid>>2, kk = (tid&3)*8;
  for (int k0 = 0; k0 < K; k0 += 32) {
    *(uint4*)&As[r][kk] = *(const uint4*)(A + (j0 + r)*(long)lda + k0 + kk);
    __syncthreads();
    s8v a = *(const s8v*)&As[wave*16 + lw][quad*8];
    #pragma unroll
    for (int nt = 0; nt < 16; nt++) {
      const int o = nt*16 + lw;
      s8v b = *(const s8v*)(W + (long)o*ldb + k0 + quad*8);
      acc[nt] = MFMA16(a, b, acc[nt]);
    }
    __syncthreads();
  }
  #pragma unroll
  for (int nt = 0; nt < 16; nt++) {
    const int o = nt*16 + lw;
    const float bv = b2f(bias[o]);
    #pragma unroll
    for (int rr = 0; rr < 4; rr++) {
      const long j = j0 + wave*16 + quad*4 + rr;
      float v = acc[nt][rr] + bv;
      if (addprev) v += skipbuf[j*256 + o];
      if (mode == 0) skipbuf[j*256 + o] = v;
      else           outb[j*256 + o] = f2b(v);
    }
  }
}

// ---------------------------------------------------------------------------
// kend: out[b,t,n] = xs@endW^T + end_b.  N=12. Output dtype per flag.
// ---------------------------------------------------------------------------
__global__ __launch_bounds__(256) void kend(
    const u16* __restrict__ A, const u16* __restrict__ W, const u16* __restrict__ bias,
    void* __restrict__ outv, const int* __restrict__ flag)
{
  __shared__ u16 As[64][40];
  const int tid = threadIdx.x, wave = tid>>6, lane = tid&63, lw = lane&15, quad = lane>>4;
  const long j0 = (long)blockIdx.x * 64;
  f4v acc = {0.f,0.f,0.f,0.f};
  const int r = tid>>2, kk = (tid&3)*8;
  for (int k0 = 0; k0 < 256; k0 += 32) {
    *(uint4*)&As[r][kk] = *(const uint4*)(A + (j0 + r)*256 + k0 + kk);
    __syncthreads();
    s8v a = *(const s8v*)&As[wave*16 + lw][quad*8];
    s8v b = {0,0,0,0,0,0,0,0};
    if (lw < 12) b = *(const s8v*)(W + lw*256 + k0 + quad*8);
    acc = MFMA16(a, b, acc);
    __syncthreads();
  }
  if (lw < 12) {
    const float bv = b2f(bias[lw]);
    const int fl = *flag;
    #pragma unroll
    for (int rr = 0; rr < 4; rr++) {
      const long j = j0 + wave*16 + quad*4 + rr;
      const long oi = (j >> 11)*24576 + lw*2048 + (j & 2047);
      const float val = acc[rr] + bv;
      if (fl) ((float*)outv)[oi] = val;
      else    ((u16*)outv)[oi]   = f2b(val);
    }
  }
}

// --------- small helpers ----------------------------------------------------
__global__ __launch_bounds__(256) void kxcl(const u16* __restrict__ src, u16* __restrict__ hid, int c0)
{
  __shared__ u16 t[32][72];
  const int tid = threadIdx.x, b = blockIdx.y, v0 = blockIdx.x*64;
  const int c = tid>>3, v8 = (tid&7)*8;
  *(uint4*)&t[c][v8] = *(const uint4*)(src + (long)b*65536 + (long)c*2048 + v0 + v8);
  __syncthreads();
  const int jl = tid>>2, c8 = (tid&3)*8;
  u16 q8[8];
  #pragma unroll
  for (int e = 0; e < 8; e++) q8[e] = t[c8 + e][jl];
  *(uint4*)(hid + ((long)b*2048 + v0 + jl)*128 + c0 + c8) = *(uint4*)q8;
}

__global__ void kcopyx(const u16* __restrict__ x, u16* __restrict__ pbuf)
{
  const int tI = blockIdx.x*256 + threadIdx.x;
  const int b = tI >> 13, rr = tI & 8191;
  *(uint4*)(pbuf + (long)b*458752 + rr*8) = *(const uint4*)(x + (long)b*65536 + rr*8);
}

__global__ __launch_bounds__(256) void krowsum(const u16* __restrict__ src, float* __restrict__ outv, int nrows)
{
  const int wave = threadIdx.x>>6, lane = threadIdx.x&63;
  const int row = blockIdx.x*4 + wave;
  if (row >= nrows) return;
  const u16* p = src + (long)row*2048 + lane*8;
  float s = 0.f;
  #pragma unroll
  for (int it = 0; it < 4; it++) {
    u16 v[8]; *(uint4*)v = *(const uint4*)(p + it*512);
    #pragma unroll
    for (int e = 0; e < 8; e++) s += b2f(v[e]);
  }
  #pragma unroll
  for (int off = 32; off; off >>= 1) s += __shfl_down(s, off, 64);
  if (lane == 0) outv[row] = 1.f/(1.f + s);
}

__global__ __launch_bounds__(256) void kcolsum(const u16* __restrict__ dy, float* __restrict__ csum)
{
  const int v = blockIdx.x*256 + threadIdx.x;
  const int b = blockIdx.z;
  const long w0 = (long)blockIdx.y*512;
  const u16* p = dy + (long)b*4194304 + w0*2048 + v;
  float s = 0.f;
  for (int w = 0; w < 512; w++) s += b2f(p[(long)w*2048]);
  atomicAdd(&csum[b*2048 + v], s);
}

__global__ void kinv(float* __restrict__ c){
  const int i = blockIdx.x*256 + threadIdx.x;
  c[i] = 1.f/(1.f + c[i]);
}

__global__ __launch_bounds__(256) void kweff(
    const u16* __restrict__ g0W, const u16* __restrict__ g1W, const u16* __restrict__ g2W,
    const u16* __restrict__ g0b, const u16* __restrict__ g1b, const u16* __restrict__ g2b,
    int ioff, int boff, u16* __restrict__ weff, float* __restrict__ bw)
{
  const int idx = blockIdx.x*256 + threadIdx.x;
  if (idx < 32) bw[idx] = b2f(g0b[boff+idx]) + b2f(g1b[boff+idx]) + b2f(g2b[boff+idx]);
  if (idx >= 7168) return;
  const int o = idx / 224, m = idx % 224;
  const u16* Ws[3] = {g0W + ioff, g1W + ioff, g2W + ioff};
  float val;
  if (m < 32) {
    val = 0.f;
    #pragma unroll
    for (int g = 0; g < 3; g++) {
      const float w0 = b2f(Ws[g][o*96 + m]);
      const float w1 = b2f(Ws[g][o*96 + 32 + m]);
      const float w2 = b2f(Ws[g][o*96 + 64 + m]);
      val += w0 + 0.05f*(w1 + w2);
    }
  } else {
    const int f = (m - 32) >> 5, cc = m & 31;
    const int g = f >> 1, typ = f & 1;
    const float w1 = b2f(Ws[g][o*96 + 32 + cc]);
    const float w2 = b2f(Ws[g][o*96 + 64 + cc]);
    val = (typ == 0) ? (0.95f*w1 + 0.0475f*w2) : (0.9025f*w2);
  }
  weff[o*224 + m] = f2b(val);
}

__global__ __launch_bounds__(256) void kstats(const float* __restrict__ xpre, float* __restrict__ stats)
{
  const int b = blockIdx.x, tid = threadIdx.x;
  const float4* p = (const float4*)(xpre + (long)b*65536);
  float s = 0.f, q = 0.f;
  for (int i = tid; i < 16384; i += 256) {
    float4 v = p[i];
    s += v.x + v.y + v.z + v.w;
    q += v.x*v.x + v.y*v.y + v.z*v.z + v.w*v.w;
  }
  __shared__ float ss[256], qq[256];
  ss[tid] = s; qq[tid] = q;
  __syncthreads();
  for (int st = 128; st; st >>= 1) {
    if (tid < st) { ss[tid] += ss[tid+st]; qq[tid] += qq[tid+st]; }
    __syncthreads();
  }
  if (tid == 0) {
    const float mu = ss[0] * (1.f/65536.f);
    const float var = qq[0] * (1.f/65536.f) - mu*mu;
    stats[b*2] = mu;
    stats[b*2+1] = rsqrtf(var + 1e-5f);
  }
}

__global__ __launch_bounds__(256) void kapply(
    const float* __restrict__ xpre, const float* __restrict__ stats,
    const u16* __restrict__ nw, const u16* __restrict__ nb,
    u16* __restrict__ slot0, u16* __restrict__ hid)
{
  __shared__ u16 t[32][72];
  const int tid = threadIdx.x, b = blockIdx.y, v0 = blockIdx.x*64;
  const float mu = stats[b*2], rs = stats[b*2+1];
  const int c = tid>>3, v8 = (tid&7)*8;
  const long boff = (long)c*2048 + v0 + v8;
  float4 xa = *(const float4*)(xpre + (long)b*65536 + boff);
  float4 xbv = *(const float4*)(xpre + (long)b*65536 + boff + 4);
  u16 wv[8], bv[8], o8[8];
  *(uint4*)wv = *(const uint4*)(nw + boff);
  *(uint4*)bv = *(const uint4*)(nb + boff);
  const float xs[8] = {xa.x, xa.y, xa.z, xa.w, xbv.x, xbv.y, xbv.z, xbv.w};
  #pragma unroll
  for (int e = 0; e < 8; e++) {
    float y = (xs[e] - mu) * rs * b2f(wv[e]) + b2f(bv[e]);
    y = fmaxf(y, 0.f);
    o8[e] = f2b(y);
    t[c][v8 + e] = o8[e];
  }
  *(uint4*)(slot0 + (long)b*458752 + boff) = *(uint4*)o8;
  __syncthreads();
  const int jl = tid>>2, c8 = (tid&3)*8;
  u16 q8[8];
  #pragma unroll
  for (int e = 0; e < 8; e++) q8[e] = t[c8 + e][jl];
  *(uint4*)(hid + ((long)b*2048 + v0 + jl)*128 + c8) = *(uint4*)q8;
}

// ---------------------------------------------------------------------------
extern "C" void kernel_launch(void* const* d_in, const int* in_sizes, int n_in,
                              void* d_out, int out_size, void* d_ws, size_t ws_size,
                              hipStream_t stream)
{
  (void)in_sizes; (void)n_in; (void)out_size; (void)ws_size;

  // workspace layout
  char* ws = (char*)d_ws;
  u16*   pbuf = (u16*)(ws + 0);          // [8][7][32][2048] bf16
  u16*   hid  = (u16*)(ws + 7340032);    // [16384][128] bf16
  u16*   hb1  = (u16*)(ws + 11534336);
  u16*   hb2  = (u16*)(ws + 15728640);
  float* skip = (float*)(ws + 19922944); // [16384][256] f32
  u16*   xsb  = (u16*)(ws + 36700160);   // [16384][256] bf16
  float* xpre = (float*)(ws + 45088768); // [8][32][2048] f32
  u16*   weff = (u16*)(ws + 47185920);
  float* bw   = (float*)(ws + 47202304);
  float* rst  = (float*)(ws + 47203328);
  float* rdy  = (float*)(ws + 47211520);
  float* cdy  = (float*)(ws + 47277056);
  float* st8  = (float*)(ws + 47342592);
  int*   flag = (int*)(ws + 47343616);

  // converted-input region (bf16 canonical copies)
  size_t coff = 50331648;
  auto alloc = [&](size_t elems) -> u16* {
    u16* p = (u16*)(ws + coff);
    coff += ((elems*2 + 255)/256)*256;
    return p;
  };
  u16* dyb   = alloc(33554432);
  u16* stgb  = alloc(4194304);
  u16* xb    = alloc(524288);
  u16* spatb = alloc(524288);
  u16* tdeb  = alloc(524288);
  u16* tweb  = alloc(524288);
  u16* encWf = alloc(98304);
  u16* encbf = alloc(768);
  u16* encWg = alloc(98304);
  u16* encbg = alloc(768);
  u16* skW   = alloc(98304);
  u16* skb   = alloc(768);
  u16* nw    = alloc(196608);
  u16* nb    = alloc(196608);
  u16* g0W   = alloc(9216);
  u16* g0b   = alloc(96);
  u16* g1W   = alloc(9216);
  u16* g1b   = alloc(96);
  u16* g2W   = alloc(9216);
  u16* g2b   = alloc(96);
  u16* sEW   = alloc(8192);
  u16* sEb   = alloc(256);
  u16* eW    = alloc(3072);
  u16* eb    = alloc(12);

  // dtype detection from x
  hipLaunchKernelGGL(kdetect, dim3(1), dim3(256), 0, stream, (const u16*)d_in[0], flag);

  // canonicalize all float inputs to bf16
  struct CV { int idx; u16* dst; int n; };
  const CV cvs[24] = {
    {0, xb, 524288}, {1, dyb, 33554432}, {2, stgb, 4194304},
    {3, spatb, 524288}, {4, tdeb, 524288}, {5, tweb, 524288},
    {6, encWf, 98304}, {7, encbf, 768}, {8, encWg, 98304}, {9, encbg, 768},
    {10, skW, 98304}, {11, skb, 768}, {12, nw, 196608}, {13, nb, 196608},
    {14, g0W, 9216}, {15, g0b, 96}, {16, g1W, 9216}, {17, g1b, 96},
    {18, g2W, 9216}, {19, g2b, 96}, {20, sEW, 8192}, {21, sEb, 256},
    {22, eW, 3072}, {23, eb, 12},
  };
  for (int t = 0; t < 24; t++) {
    const int n4 = cvs[t].n / 4;
    hipLaunchKernelGGL(kcvt4, dim3((n4 + 255)/256), dim3(256), 0, stream,
        d_in[cvs[t].idx], cvs[t].dst, n4, flag);
  }

  const long PB = 458752;
  const long SL = 65536;
  const long DYB = 4194304;

  hipMemsetAsync(cdy, 0, 65536, stream);
  hipLaunchKernelGGL(kxcl, dim3(32,8), dim3(256), 0, stream, xb,    hid, 0);
  hipLaunchKernelGGL(kxcl, dim3(32,8), dim3(256), 0, stream, spatb, hid, 32);
  hipLaunchKernelGGL(kxcl, dim3(32,8), dim3(256), 0, stream, tdeb,  hid, 64);
  hipLaunchKernelGGL(kxcl, dim3(32,8), dim3(256), 0, stream, tweb,  hid, 96);
  hipLaunchKernelGGL(kcopyx, dim3(256), dim3(256), 0, stream, xb, pbuf);
  hipLaunchKernelGGL(krowsum, dim3(4096), dim3(256), 0, stream, dyb,  rdy, 16384);
  hipLaunchKernelGGL(krowsum, dim3(512),  dim3(256), 0, stream, stgb, rst, 2048);
  hipLaunchKernelGGL(kcolsum, dim3(8,4,8), dim3(256), 0, stream, dyb, cdy);
  hipLaunchKernelGGL(kinv, dim3(64), dim3(256), 0, stream, cdy);

  for (int i = 0; i < 3; i++) {
    hipLaunchKernelGGL(ktcn, dim3(256), dim3(256), 0, stream,
        hid, encWf + (i*2+0)*16384, encbf + (i*2+0)*128, encWg + (i*2+0)*16384, encbg + (i*2+0)*128, hb1);
    hipLaunchKernelGGL(ktcn, dim3(256), dim3(256), 0, stream,
        hb1, encWf + (i*2+1)*16384, encbf + (i*2+1)*128, encWg + (i*2+1)*16384, encbg + (i*2+1)*128, hb2);
    hipLaunchKernelGGL(kskip, dim3(256), dim3(256), 0, stream,
        hb2, 128, 128, skW + i*32768, 128, skb + i*256, skip, (i>0)?1:0, 0, (u16*)nullptr);
    hipLaunchKernelGGL(kweff, dim3(28), dim3(256), 0, stream,
        g0W, g1W, g2W, g0b, g1b, g2b, i*3072, i*32, weff, bw);
    // p1 = normprop(x) for static / adp / adp^T
    hipLaunchKernelGGL((kprop<0,0>), dim3(128,8,1), dim3(256), 0, stream,
        stgb, 0L, 2048, 2048, pbuf, PB, 2048, pbuf, PB, rst, 0L, (const float*)nullptr, pbuf + 1*SL, (float*)nullptr, PB);
    hipLaunchKernelGGL((kprop<0,0>), dim3(128,1,8), dim3(256), 0, stream,
        dyb, DYB, 2048, 2048, pbuf, PB, 2048, pbuf, PB, rdy, 2048L, (const float*)nullptr, pbuf + 3*SL, (float*)nullptr, PB);
    hipLaunchKernelGGL((kprop<1,0>), dim3(128,1,8), dim3(256), 0, stream,
        dyb, DYB, 2048, 2048, pbuf, PB, 2048, pbuf, PB, cdy, 2048L, (const float*)nullptr, pbuf + 5*SL, (float*)nullptr, PB);
    // p2 = normprop(p1)
    hipLaunchKernelGGL((kprop<0,0>), dim3(128,8,1), dim3(256), 0, stream,
        stgb, 0L, 2048, 2048, pbuf + 1*SL, PB, 2048, pbuf + 1*SL, PB, rst, 0L, (const float*)nullptr, pbuf + 2*SL, (float*)nullptr, PB);
    hipLaunchKernelGGL((kprop<0,0>), dim3(128,1,8), dim3(256), 0, stream,
        dyb, DYB, 2048, 2048, pbuf + 3*SL, PB, 2048, pbuf + 3*SL, PB, rdy, 2048L, (const float*)nullptr, pbuf + 4*SL, (float*)nullptr, PB);
    hipLaunchKernelGGL((kprop<1,0>), dim3(128,1,8), dim3(256), 0, stream,
        dyb, DYB, 2048, 2048, pbuf + 5*SL, PB, 2048, pbuf + 5*SL, PB, cdy, 2048L, (const float*)nullptr, pbuf + 6*SL, (float*)nullptr, PB);
    // combine: xpre = Weff @ [x,p1..p2] + bias + residual
    hipLaunchKernelGGL((kprop<1,1>), dim3(128,1,8), dim3(256), 0, stream,
        pbuf, PB, 2048, 224, weff, 0L, 224, pbuf, PB, (const float*)nullptr, 0L, bw, (u16*)nullptr, xpre, 65536L);
    hipLaunchKernelGGL(kstats, dim3(8), dim3(256), 0, stream, xpre, st8);
    hipLaunchKernelGGL(kapply, dim3(32,8), dim3(256), 0, stream,
        xpre, st8, nw + i*65536, nb + i*65536, pbuf, hid);
  }
  hipLaunchKernelGGL(kskip, dim3(256), dim3(256), 0, stream,
      hid, 128, 32, sEW, 32, sEb, skip, 1, 1, xsb);
  hipLaunchKernelGGL(kend, dim3(256), dim3(256), 0, stream, xsb, eW, eb, d_out, flag);
}

// Round 3
// 1104.703 us; speedup vs baseline: 1.0728x; 1.0728x over previous
//
#include <hip/hip_runtime.h>
#include <stdint.h>

// Net_18021682774696 — MTGNN-ish: 3x { TCN(2 gated units) ; skip ; 3x mixprop ; LN+ReLU } + end convs.
// Round 3: LDS-free direct-fragment prop kernel (deep MLP), materialized dy^T,
// fused convert+transpose+row/col-sums, LDS-free small GEMMs, consolidated converts.

typedef uint16_t u16;
typedef uint32_t u32;
typedef __attribute__((ext_vector_type(8))) short s8v;
typedef __attribute__((ext_vector_type(4))) float f4v;

#define MFMA16(a,b,c) __builtin_amdgcn_mfma_f32_16x16x32_bf16(a,b,c,0,0,0)

__device__ __forceinline__ float b2f(u16 u){ union{u32 i; float f;} x; x.i=(u32)u<<16; return x.f; }
__device__ __forceinline__ u16 f2b(float f){
  u32 u = __builtin_bit_cast(u32, f);
  u32 r = (u + 0x7fffu + ((u >> 16) & 1u)) >> 16;   // RNE
  return (u16)r;
}

// ---------------------------------------------------------------------------
// kdetect: fp32 (flag=1) vs bf16 (flag=0) input detection (see round 2).
// ---------------------------------------------------------------------------
__global__ __launch_bounds__(256) void kdetect(const u16* __restrict__ x, int* __restrict__ flag)
{
  const int i = threadIdx.x;
  int cnt = 0;
  for (int k = i; k < 65536; k += 256) {
    const u16 v = x[k];
    if ((v & 0x7F80u) == 0x7F80u) cnt++;
  }
  __shared__ int s[256];
  s[i] = cnt; __syncthreads();
  for (int st = 128; st; st >>= 1) { if (i < st) s[i] += s[i+st]; __syncthreads(); }
  if (i == 0) flag[0] = (s[0] > 0) ? 1 : 0;
}

// kcvt4: canonicalize one array into bf16 (4 elements/thread).
__global__ __launch_bounds__(256) void kcvt4(const void* __restrict__ src, u16* __restrict__ dst,
                                             int n4, const int* __restrict__ flag)
{
  const int i = blockIdx.x*256 + threadIdx.x;
  if (i >= n4) return;
  if (*flag) {
    const float4 v = ((const float4*)src)[i];
    u16 o[4]; o[0]=f2b(v.x); o[1]=f2b(v.y); o[2]=f2b(v.z); o[3]=f2b(v.w);
    *(uint2*)(dst + (long)i*4) = *(uint2*)o;
  } else {
    *(uint2*)(dst + (long)i*4) = ((const uint2*)src)[i];
  }
}

// kcvt_small: all 22 small inputs in one launch (table passed by value).
struct CvtTab { const void* s[22]; u16* d[22]; int n4[22]; };
__global__ __launch_bounds__(256) void kcvt_small(CvtTab tb, const int* __restrict__ flag)
{
  const int e = blockIdx.y;
  const int i = blockIdx.x*256 + threadIdx.x;
  if (i >= tb.n4[e]) return;
  if (*flag) {
    const float4 v = ((const float4*)tb.s[e])[i];
    u16 o[4]; o[0]=f2b(v.x); o[1]=f2b(v.y); o[2]=f2b(v.z); o[3]=f2b(v.w);
    *(uint2*)(tb.d[e] + (long)i*4) = *(uint2*)o;
  } else {
    *(uint2*)(tb.d[e] + (long)i*4) = ((const uint2*)tb.s[e])[i];
  }
}

// ---------------------------------------------------------------------------
// kcvtT: dy -> dyb (bf16) + dytb (bf16 transposed) + row/col sum atomics.
//   64x64 tiles via LDS; rsum/csum must be pre-zeroed.
// ---------------------------------------------------------------------------
__global__ __launch_bounds__(256) void kcvtT(
    const void* __restrict__ src, u16* __restrict__ dyb, u16* __restrict__ dytb,
    float* __restrict__ rsum, float* __restrict__ csum, const int* __restrict__ flag)
{
  __shared__ u16 t[64][68];
  const int tid = threadIdx.x;
  const int b = blockIdx.z;
  const long r0 = (long)blockIdx.y*64, c0 = (long)blockIdx.x*64;
  const int r = tid>>2, cs16 = (tid&3)*16;
  const long base = (long)b*4194304;
  u16 v16[16];
  if (*flag) {
    const float* sp = (const float*)src + base + (r0+r)*2048 + c0 + cs16;
    #pragma unroll
    for (int q=0; q<4; q++) {
      float4 f = *(const float4*)(sp + q*4);
      v16[q*4+0]=f2b(f.x); v16[q*4+1]=f2b(f.y); v16[q*4+2]=f2b(f.z); v16[q*4+3]=f2b(f.w);
    }
  } else {
    const u16* sp = (const u16*)src + base + (r0+r)*2048 + c0 + cs16;
    *(uint4*)&v16[0] = *(const uint4*)sp;
    *(uint4*)&v16[8] = *(const uint4*)(sp+8);
  }
  *(uint4*)(dyb + base + (r0+r)*2048 + c0 + cs16)     = *(uint4*)&v16[0];
  *(uint4*)(dyb + base + (r0+r)*2048 + c0 + cs16 + 8) = *(uint4*)&v16[8];
  float s = 0.f;
  #pragma unroll
  for (int e=0; e<16; e++) s += b2f(v16[e]);
  #pragma unroll
  for (int q=0; q<4; q++) *(uint2*)&t[r][cs16+q*4] = *(uint2*)&v16[q*4];
  s += __shfl_down(s, 2, 64);
  s += __shfl_down(s, 1, 64);
  if ((tid&3)==0) atomicAdd(rsum + b*2048 + r0 + r, s);
  __syncthreads();
  const int c = tid>>2, rs16 = (tid&3)*16;
  u16 w16[16]; float cssum = 0.f;
  #pragma unroll
  for (int e=0; e<16; e++) { w16[e] = t[rs16+e][c]; cssum += b2f(w16[e]); }
  *(uint4*)(dytb + base + (c0+c)*2048 + r0 + rs16)     = *(uint4*)&w16[0];
  *(uint4*)(dytb + base + (c0+c)*2048 + r0 + rs16 + 8) = *(uint4*)&w16[8];
  cssum += __shfl_down(cssum, 2, 64);
  cssum += __shfl_down(cssum, 1, 64);
  if ((tid&3)==0) atomicAdd(csum + b*2048 + c0 + c, cssum);
}

__global__ void kfin(float* __restrict__ v){   // v = 1/(1+v), 32768 elems
  const int i = blockIdx.x*256 + threadIdx.x;
  v[i] = 1.f/(1.f + v[i]);
}

// ---------------------------------------------------------------------------
// kpropf: out[v,c] = (sum_k A[v,k] X[c,k] + D[c,v]) * rinv[v]  -> bf16
//   LDS-free: A-fragment (16B contiguous per lane) loaded direct from global.
//   Block = 16-row v-tile; K=2048 split across the 4 waves (512 each);
//   unroll x4 -> 12 outstanding 16B loads/wave. LDS only for final reduction.
// ---------------------------------------------------------------------------
__global__ __launch_bounds__(256, 4) void kpropf(
    const u16* __restrict__ A, long a_bs,
    const u16* __restrict__ X, long x_bs,
    const u16* __restrict__ D, long d_bs,
    const float* __restrict__ rinv, long r_bs,
    u16* __restrict__ out0, long o_bs)
{
  __shared__ f4v red[4][2][64];
  const int tid = threadIdx.x, wave = tid>>6, lane = tid&63;
  const int lw = lane&15, quad = lane>>4;
  const int v0 = blockIdx.x*16;
  const int b = blockIdx.y;
  const u16* Arow = A + (long)b*a_bs + (long)(v0+lw)*2048 + quad*8;
  const u16* Xb = X + (long)b*x_bs + quad*8;
  f4v acc0 = {0.f,0.f,0.f,0.f}, acc1 = {0.f,0.f,0.f,0.f};
  const int kbase = wave*512;
  #pragma unroll 1
  for (int cc = 0; cc < 16; cc += 4) {
    s8v a[4], b0[4], b1[4];
    #pragma unroll
    for (int u = 0; u < 4; u++) {
      const int k = kbase + (cc+u)*32;
      a[u]  = *(const s8v*)(Arow + k);
      b0[u] = *(const s8v*)(Xb + (long)lw*2048 + k);
      b1[u] = *(const s8v*)(Xb + (long)(16+lw)*2048 + k);
    }
    #pragma unroll
    for (int u = 0; u < 4; u++) {
      acc0 = MFMA16(a[u], b0[u], acc0);
      acc1 = MFMA16(a[u], b1[u], acc1);
    }
  }
  red[wave][0][lane] = acc0;
  red[wave][1][lane] = acc1;
  __syncthreads();
  if (wave == 0) {
    const int vb = v0 + quad*4;
    #pragma unroll
    for (int nt = 0; nt < 2; nt++) {
      f4v a = red[0][nt][lane] + red[1][nt][lane] + red[2][nt][lane] + red[3][nt][lane];
      const int c = nt*16 + lw;
      const u16* dp = D + (long)b*d_bs + (long)c*2048 + vb;
      const float* rp = rinv + (long)b*r_bs + vb;
      u16 pk[4];
      #pragma unroll
      for (int r = 0; r < 4; r++) pk[r] = f2b((a[r] + b2f(dp[r])) * rp[r]);
      *(uint2*)(out0 + (long)b*o_bs + (long)c*2048 + vb) = *(uint2*)pk;
    }
  }
}

// ---------------------------------------------------------------------------
// kprop (round-2 template, kept for the TRANSA=1 combine pass only):
//   MODE 1: out = acc + bias[c] + D[c,v] -> f32
// ---------------------------------------------------------------------------
template<int TRANSA, int MODE>
__global__ __launch_bounds__(256) void kprop(
    const u16* __restrict__ A, long a_bs, int lda, int K,
    const u16* __restrict__ X, long x_bs, int ldx,
    const u16* __restrict__ D, long d_bs,
    const float* __restrict__ rinv, long r_bs,
    const float* __restrict__ bias,
    u16* __restrict__ out0, float* __restrict__ out1, long o_bs)
{
  __shared__ u16 As[4][2][16][40];
  __shared__ f4v red[4][2][64];
  const int tid = threadIdx.x;
  const int wave = tid >> 6, lane = tid & 63;
  const int lw = lane & 15, quad = lane >> 4;
  const int v0 = blockIdx.x * 16;
  const int ball = blockIdx.z + blockIdx.y;
  const u16* Ab = A + (long)ball * a_bs;
  const u16* Xb = X + (long)ball * x_bs;
  const int KC = K >> 5;

  f4v acc0 = {0.f,0.f,0.f,0.f}, acc1 = {0.f,0.f,0.f,0.f};

  int r0, c0_;
  if (TRANSA == 0) { r0 = lane >> 2; c0_ = (lane & 3) * 8; }
  else             { r0 = lane >> 1; c0_ = (lane & 1) * 8; }

  int ci = wave;
  bool has = ci < KC;
  uint4 d = make_uint4(0,0,0,0);
  if (has) {
    d = (TRANSA == 0)
      ? *(const uint4*)(Ab + (long)(v0 + r0) * lda + ci * 32 + c0_)
      : *(const uint4*)(Ab + (long)(ci * 32 + r0) * lda + v0 + c0_);
  }
  int buf = 0;
  while (has) {
    if (TRANSA == 0) {
      *(uint4*)&As[wave][buf][r0][c0_] = d;
    } else {
      u16 tmp[8]; *(uint4*)tmp = d;
      #pragma unroll
      for (int e = 0; e < 8; e++) As[wave][buf][c0_ + e][r0] = tmp[e];
    }
    const int cn = ci + 4;
    const bool hn = cn < KC;
    if (hn) {
      d = (TRANSA == 0)
        ? *(const uint4*)(Ab + (long)(v0 + r0) * lda + cn * 32 + c0_)
        : *(const uint4*)(Ab + (long)(cn * 32 + r0) * lda + v0 + c0_);
    }
    s8v af = *(const s8v*)&As[wave][buf][lw][quad * 8];
    const u16* xk = Xb + ci * 32 + quad * 8;
    s8v b0 = *(const s8v*)(xk + (long)lw * ldx);
    s8v b1 = *(const s8v*)(xk + (long)(16 + lw) * ldx);
    acc0 = MFMA16(af, b0, acc0);
    acc1 = MFMA16(af, b1, acc1);
    ci = cn; has = hn; buf ^= 1;
  }
  red[wave][0][lane] = acc0;
  red[wave][1][lane] = acc1;
  __syncthreads();
  if (wave == 0) {
    const int vb = v0 + quad * 4;
    #pragma unroll
    for (int nt = 0; nt < 2; nt++) {
      f4v a = red[0][nt][lane] + red[1][nt][lane] + red[2][nt][lane] + red[3][nt][lane];
      const int c = nt * 16 + lw;
      const u16* dp = D + (long)ball * d_bs + (long)c * 2048 + vb;
      if (MODE == 0) {
        const float* rp = rinv + (long)ball * r_bs + vb;
        u16 pk[4];
        #pragma unroll
        for (int r = 0; r < 4; r++) pk[r] = f2b((a[r] + b2f(dp[r])) * rp[r]);
        *(uint2*)(out0 + (long)ball * o_bs + (long)c * 2048 + vb) = *(uint2*)pk;
      } else {
        const float bs = bias[c];
        float4 st;
        st.x = a[0] + bs + b2f(dp[0]);
        st.y = a[1] + bs + b2f(dp[1]);
        st.z = a[2] + bs + b2f(dp[2]);
        st.w = a[3] + bs + b2f(dp[3]);
        *(float4*)(out1 + (long)ball * o_bs + (long)c * 2048 + vb) = st;
      }
    }
  }
}

// ---------------------------------------------------------------------------
// ktcn (LDS-free): out[j,o] = tanh(H@Wf^T+bf)*sigmoid(H@Wg^T+bg); wave=16 rows.
// ---------------------------------------------------------------------------
__global__ __launch_bounds__(256) void ktcn(
    const u16* __restrict__ H, const u16* __restrict__ Wf, const u16* __restrict__ bfv,
    const u16* __restrict__ Wg, const u16* __restrict__ bgv, u16* __restrict__ out)
{
  const int tid = threadIdx.x, wave = tid>>6, lane = tid&63, lw = lane&15, quad = lane>>4;
  const long j0 = (long)blockIdx.x*64 + wave*16;
  const f4v zero = {0.f,0.f,0.f,0.f};
  f4v accf[8], accg[8];
  #pragma unroll
  for (int nt=0; nt<8; nt++){ accf[nt] = zero; accg[nt] = zero; }
  const u16* Arow = H + (j0 + lw)*128 + quad*8;
  #pragma unroll
  for (int k0 = 0; k0 < 128; k0 += 32) {
    s8v a = *(const s8v*)(Arow + k0);
    #pragma unroll
    for (int nt = 0; nt < 8; nt++) {
      const int o = nt*16 + lw;
      s8v bf_ = *(const s8v*)(Wf + o*128 + k0 + quad*8);
      s8v bg_ = *(const s8v*)(Wg + o*128 + k0 + quad*8);
      accf[nt] = MFMA16(a, bf_, accf[nt]);
      accg[nt] = MFMA16(a, bg_, accg[nt]);
    }
  }
  #pragma unroll
  for (int nt = 0; nt < 8; nt++) {
    const int o = nt*16 + lw;
    const float fb = b2f(bfv[o]), gb = b2f(bgv[o]);
    #pragma unroll
    for (int rr = 0; rr < 4; rr++) {
      const long j = j0 + quad*4 + rr;
      const float f = accf[nt][rr] + fb, g = accg[nt][rr] + gb;
      const float e2 = __expf(2.f*f);
      const float th = 1.f - 2.f/(e2 + 1.f);
      const float sg = 1.f/(1.f + __expf(-g));
      out[j*128 + o] = f2b(th*sg);
    }
  }
}

// ---------------------------------------------------------------------------
// kskip (LDS-free): C[j,o] = A@W^T + bias (+ prev skip).  N=256.
// ---------------------------------------------------------------------------
__global__ __launch_bounds__(256) void kskip(
    const u16* __restrict__ A, int lda, int K,
    const u16* __restrict__ W, int ldb,
    const u16* __restrict__ bias,
    float* __restrict__ skipbuf, int addprev, int mode, u16* __restrict__ outb)
{
  const int tid = threadIdx.x, wave = tid>>6, lane = tid&63, lw = lane&15, quad = lane>>4;
  const long j0 = (long)blockIdx.x*64 + wave*16;
  const f4v zero = {0.f,0.f,0.f,0.f};
  f4v acc[16];
  #pragma unroll
  for (int nt=0; nt<16; nt++) acc[nt] = zero;
  const u16* Arow = A + (j0 + lw)*(long)lda + quad*8;
  for (int k0 = 0; k0 < K; k0 += 32) {
    s8v a = *(const s8v*)(Arow + k0);
    #pragma unroll
    for (int nt = 0; nt < 16; nt++) {
      const int o = nt*16 + lw;
      s8v b = *(const s8v*)(W + (long)o*ldb + k0 + quad*8);
      acc[nt] = MFMA16(a, b, acc[nt]);
    }
  }
  #pragma unroll
  for (int nt = 0; nt < 16; nt++) {
    const int o = nt*16 + lw;
    const float bv = b2f(bias[o]);
    #pragma unroll
    for (int rr = 0; rr < 4; rr++) {
      const long j = j0 + quad*4 + rr;
      float v = acc[nt][rr] + bv;
      if (addprev) v += skipbuf[j*256 + o];
      if (mode == 0) skipbuf[j*256 + o] = v;
      else           outb[j*256 + o] = f2b(v);
    }
  }
}

// ---------------------------------------------------------------------------
// kend (LDS-free): out[b,t,n] = xs@endW^T + end_b.  N=12, K=256.
// ---------------------------------------------------------------------------
__global__ __launch_bounds__(256) void kend(
    const u16* __restrict__ A, const u16* __restrict__ W, const u16* __restrict__ bias,
    void* __restrict__ outv, const int* __restrict__ flag)
{
  const int tid = threadIdx.x, wave = tid>>6, lane = tid&63, lw = lane&15, quad = lane>>4;
  const long j0 = (long)blockIdx.x*64 + wave*16;
  f4v acc = {0.f,0.f,0.f,0.f};
  const u16* Arow = A + (j0 + lw)*256 + quad*8;
  #pragma unroll
  for (int k0 = 0; k0 < 256; k0 += 32) {
    s8v a = *(const s8v*)(Arow + k0);
    s8v b = {0,0,0,0,0,0,0,0};
    if (lw < 12) b = *(const s8v*)(W + lw*256 + k0 + quad*8);
    acc = MFMA16(a, b, acc);
  }
  if (lw < 12) {
    const float bv = b2f(bias[lw]);
    const int fl = *flag;
    #pragma unroll
    for (int rr = 0; rr < 4; rr++) {
      const long j = j0 + quad*4 + rr;
      const long oi = (j >> 11)*24576 + lw*2048 + (j & 2047);
      const float val = acc[rr] + bv;
      if (fl) ((float*)outv)[oi] = val;
      else    ((u16*)outv)[oi]   = f2b(val);
    }
  }
}

// --------- small helpers ----------------------------------------------------
__global__ __launch_bounds__(256) void kxcl(const u16* __restrict__ src, u16* __restrict__ hid, int c0)
{
  __shared__ u16 t[32][72];
  const int tid = threadIdx.x, b = blockIdx.y, v0 = blockIdx.x*64;
  const int c = tid>>3, v8 = (tid&7)*8;
  *(uint4*)&t[c][v8] = *(const uint4*)(src + (long)b*65536 + (long)c*2048 + v0 + v8);
  __syncthreads();
  const int jl = tid>>2, c8 = (tid&3)*8;
  u16 q8[8];
  #pragma unroll
  for (int e = 0; e < 8; e++) q8[e] = t[c8 + e][jl];
  *(uint4*)(hid + ((long)b*2048 + v0 + jl)*128 + c0 + c8) = *(uint4*)q8;
}

__global__ void kcopyx(const u16* __restrict__ x, u16* __restrict__ pbuf)
{
  const int tI = blockIdx.x*256 + threadIdx.x;
  const int b = tI >> 13, rr = tI & 8191;
  *(uint4*)(pbuf + (long)b*458752 + rr*8) = *(const uint4*)(x + (long)b*65536 + rr*8);
}

__global__ __launch_bounds__(256) void krowsum(const u16* __restrict__ src, float* __restrict__ outv, int nrows)
{
  const int wave = threadIdx.x>>6, lane = threadIdx.x&63;
  const int row = blockIdx.x*4 + wave;
  if (row >= nrows) return;
  const u16* p = src + (long)row*2048 + lane*8;
  float s = 0.f;
  #pragma unroll
  for (int it = 0; it < 4; it++) {
    u16 v[8]; *(uint4*)v = *(const uint4*)(p + it*512);
    #pragma unroll
    for (int e = 0; e < 8; e++) s += b2f(v[e]);
  }
  #pragma unroll
  for (int off = 32; off; off >>= 1) s += __shfl_down(s, off, 64);
  if (lane == 0) outv[row] = 1.f/(1.f + s);
}

__global__ __launch_bounds__(256) void kweff(
    const u16* __restrict__ g0W, const u16* __restrict__ g1W, const u16* __restrict__ g2W,
    const u16* __restrict__ g0b, const u16* __restrict__ g1b, const u16* __restrict__ g2b,
    int ioff, int boff, u16* __restrict__ weff, float* __restrict__ bw)
{
  const int idx = blockIdx.x*256 + threadIdx.x;
  if (idx < 32) bw[idx] = b2f(g0b[boff+idx]) + b2f(g1b[boff+idx]) + b2f(g2b[boff+idx]);
  if (idx >= 7168) return;
  const int o = idx / 224, m = idx % 224;
  const u16* Ws[3] = {g0W + ioff, g1W + ioff, g2W + ioff};
  float val;
  if (m < 32) {
    val = 0.f;
    #pragma unroll
    for (int g = 0; g < 3; g++) {
      const float w0 = b2f(Ws[g][o*96 + m]);
      const float w1 = b2f(Ws[g][o*96 + 32 + m]);
      const float w2 = b2f(Ws[g][o*96 + 64 + m]);
      val += w0 + 0.05f*(w1 + w2);
    }
  } else {
    const int f = (m - 32) >> 5, cc = m & 31;
    const int g = f >> 1, typ = f & 1;
    const float w1 = b2f(Ws[g][o*96 + 32 + cc]);
    const float w2 = b2f(Ws[g][o*96 + 64 + cc]);
    val = (typ == 0) ? (0.95f*w1 + 0.0475f*w2) : (0.9025f*w2);
  }
  weff[o*224 + m] = f2b(val);
}

__global__ __launch_bounds__(256) void kstats(const float* __restrict__ xpre, float* __restrict__ stats)
{
  const int b = blockIdx.x, tid = threadIdx.x;
  const float4* p = (const float4*)(xpre + (long)b*65536);
  float s = 0.f, q = 0.f;
  for (int i = tid; i < 16384; i += 256) {
    float4 v = p[i];
    s += v.x + v.y + v.z + v.w;
    q += v.x*v.x + v.y*v.y + v.z*v.z + v.w*v.w;
  }
  __shared__ float ss[256], qq[256];
  ss[tid] = s; qq[tid] = q;
  __syncthreads();
  for (int st = 128; st; st >>= 1) {
    if (tid < st) { ss[tid] += ss[tid+st]; qq[tid] += qq[tid+st]; }
    __syncthreads();
  }
  if (tid == 0) {
    const float mu = ss[0] * (1.f/65536.f);
    const float var = qq[0] * (1.f/65536.f) - mu*mu;
    stats[b*2] = mu;
    stats[b*2+1] = rsqrtf(var + 1e-5f);
  }
}

__global__ __launch_bounds__(256) void kapply(
    const float* __restrict__ xpre, const float* __restrict__ stats,
    const u16* __restrict__ nw, const u16* __restrict__ nb,
    u16* __restrict__ slot0, u16* __restrict__ hid)
{
  __shared__ u16 t[32][72];
  const int tid = threadIdx.x, b = blockIdx.y, v0 = blockIdx.x*64;
  const float mu = stats[b*2], rs = stats[b*2+1];
  const int c = tid>>3, v8 = (tid&7)*8;
  const long boff = (long)c*2048 + v0 + v8;
  float4 xa = *(const float4*)(xpre + (long)b*65536 + boff);
  float4 xbv = *(const float4*)(xpre + (long)b*65536 + boff + 4);
  u16 wv[8], bv[8], o8[8];
  *(uint4*)wv = *(const uint4*)(nw + boff);
  *(uint4*)bv = *(const uint4*)(nb + boff);
  const float xs[8] = {xa.x, xa.y, xa.z, xa.w, xbv.x, xbv.y, xbv.z, xbv.w};
  #pragma unroll
  for (int e = 0; e < 8; e++) {
    float y = (xs[e] - mu) * rs * b2f(wv[e]) + b2f(bv[e]);
    y = fmaxf(y, 0.f);
    o8[e] = f2b(y);
    t[c][v8 + e] = o8[e];
  }
  *(uint4*)(slot0 + (long)b*458752 + boff) = *(uint4*)o8;
  __syncthreads();
  const int jl = tid>>2, c8 = (tid&3)*8;
  u16 q8[8];
  #pragma unroll
  for (int e = 0; e < 8; e++) q8[e] = t[c8 + e][jl];
  *(uint4*)(hid + ((long)b*2048 + v0 + jl)*128 + c8) = *(uint4*)q8;
}

// ---------------------------------------------------------------------------
extern "C" void kernel_launch(void* const* d_in, const int* in_sizes, int n_in,
                              void* d_out, int out_size, void* d_ws, size_t ws_size,
                              hipStream_t stream)
{
  (void)in_sizes; (void)n_in; (void)out_size; (void)ws_size;

  char* ws = (char*)d_ws;
  u16*   pbuf = (u16*)(ws + 0);          // [8][7][32][2048] bf16
  u16*   hid  = (u16*)(ws + 7340032);    // [16384][128] bf16
  u16*   hb1  = (u16*)(ws + 11534336);
  u16*   hb2  = (u16*)(ws + 15728640);
  float* skip = (float*)(ws + 19922944); // [16384][256] f32
  u16*   xsb  = (u16*)(ws + 36700160);   // [16384][256] bf16
  float* xpre = (float*)(ws + 45088768); // [8][32][2048] f32
  u16*   weff = (u16*)(ws + 47185920);
  float* bw   = (float*)(ws + 47202304);
  float* rst  = (float*)(ws + 47203328); // [2048]
  float* rdy  = (float*)(ws + 47211520); // [8][2048]  (contiguous with cdy)
  float* cdy  = (float*)(ws + 47277056); // [8][2048]
  float* st8  = (float*)(ws + 47342592);
  int*   flag = (int*)(ws + 47343616);

  size_t coff = 50331648;
  auto alloc = [&](size_t elems) -> u16* {
    u16* p = (u16*)(ws + coff);
    coff += ((elems*2 + 255)/256)*256;
    return p;
  };
  u16* dyb   = alloc(33554432);
  u16* stgb  = alloc(4194304);
  u16* xb    = alloc(524288);
  u16* spatb = alloc(524288);
  u16* tdeb  = alloc(524288);
  u16* tweb  = alloc(524288);
  u16* encWf = alloc(98304);
  u16* encbf = alloc(768);
  u16* encWg = alloc(98304);
  u16* encbg = alloc(768);
  u16* skW   = alloc(98304);
  u16* skb   = alloc(768);
  u16* nw    = alloc(196608);
  u16* nb    = alloc(196608);
  u16* g0W   = alloc(9216);
  u16* g0b   = alloc(96);
  u16* g1W   = alloc(9216);
  u16* g1b   = alloc(96);
  u16* g2W   = alloc(9216);
  u16* g2b   = alloc(96);
  u16* sEW   = alloc(8192);
  u16* sEb   = alloc(256);
  u16* eW    = alloc(3072);
  u16* eb    = alloc(12);
  u16* dytb  = alloc(33554432);          // dy^T bf16 (~198 MB total, ws is 512 MiB)

  hipLaunchKernelGGL(kdetect, dim3(1), dim3(256), 0, stream, (const u16*)d_in[0], flag);

  // small inputs in one launch
  CvtTab tb;
  {
    const void* ss[22] = { d_in[0], d_in[3], d_in[4], d_in[5],
      d_in[6], d_in[7], d_in[8], d_in[9], d_in[10], d_in[11], d_in[12], d_in[13],
      d_in[14], d_in[15], d_in[16], d_in[17], d_in[18], d_in[19], d_in[20], d_in[21],
      d_in[22], d_in[23] };
    u16* dd[22] = { xb, spatb, tdeb, tweb, encWf, encbf, encWg, encbg, skW, skb,
      nw, nb, g0W, g0b, g1W, g1b, g2W, g2b, sEW, sEb, eW, eb };
    const int nn[22] = { 131072, 131072, 131072, 131072, 24576, 192, 24576, 192,
      24576, 192, 49152, 49152, 2304, 24, 2304, 24, 2304, 24, 2048, 64, 768, 3 };
    for (int e = 0; e < 22; e++) { tb.s[e] = ss[e]; tb.d[e] = dd[e]; tb.n4[e] = nn[e]; }
  }
  hipLaunchKernelGGL(kcvt_small, dim3(512, 22), dim3(256), 0, stream, tb, flag);
  hipLaunchKernelGGL(kcvt4, dim3(4096), dim3(256), 0, stream, d_in[2], stgb, 1048576, flag);

  hipMemsetAsync(rdy, 0, 131072, stream);   // zeroes rdy+cdy (contiguous)
  hipLaunchKernelGGL(kcvtT, dim3(32,32,8), dim3(256), 0, stream,
      d_in[1], dyb, dytb, rdy, cdy, flag);
  hipLaunchKernelGGL(kfin, dim3(128), dim3(256), 0, stream, rdy);
  hipLaunchKernelGGL(krowsum, dim3(512), dim3(256), 0, stream, stgb, rst, 2048);

  hipLaunchKernelGGL(kxcl, dim3(32,8), dim3(256), 0, stream, xb,    hid, 0);
  hipLaunchKernelGGL(kxcl, dim3(32,8), dim3(256), 0, stream, spatb, hid, 32);
  hipLaunchKernelGGL(kxcl, dim3(32,8), dim3(256), 0, stream, tdeb,  hid, 64);
  hipLaunchKernelGGL(kxcl, dim3(32,8), dim3(256), 0, stream, tweb,  hid, 96);
  hipLaunchKernelGGL(kcopyx, dim3(256), dim3(256), 0, stream, xb, pbuf);

  const long PB = 458752;
  const long SL = 65536;
  const long DYB = 4194304;

  for (int i = 0; i < 3; i++) {
    hipLaunchKernelGGL(ktcn, dim3(256), dim3(256), 0, stream,
        hid, encWf + (i*2+0)*16384, encbf + (i*2+0)*128, encWg + (i*2+0)*16384, encbg + (i*2+0)*128, hb1);
    hipLaunchKernelGGL(ktcn, dim3(256), dim3(256), 0, stream,
        hb1, encWf + (i*2+1)*16384, encbf + (i*2+1)*128, encWg + (i*2+1)*16384, encbg + (i*2+1)*128, hb2);
    hipLaunchKernelGGL(kskip, dim3(256), dim3(256), 0, stream,
        hb2, 128, 128, skW + i*32768, 128, skb + i*256, skip, (i>0)?1:0, 0, (u16*)nullptr);
    hipLaunchKernelGGL(kweff, dim3(28), dim3(256), 0, stream,
        g0W, g1W, g2W, g0b, g1b, g2b, i*3072, i*32, weff, bw);
    // p1 hops (static fwd, dy fwd, dy^T fwd via dytb)
    hipLaunchKernelGGL(kpropf, dim3(128,8), dim3(256), 0, stream,
        stgb, 0L, pbuf, PB, pbuf, PB, rst, 0L, pbuf + 1*SL, PB);
    hipLaunchKernelGGL(kpropf, dim3(128,8), dim3(256), 0, stream,
        dyb, DYB, pbuf, PB, pbuf, PB, rdy, 2048L, pbuf + 3*SL, PB);
    hipLaunchKernelGGL(kpropf, dim3(128,8), dim3(256), 0, stream,
        dytb, DYB, pbuf, PB, pbuf, PB, cdy, 2048L, pbuf + 5*SL, PB);
    // p2 hops
    hipLaunchKernelGGL(kpropf, dim3(128,8), dim3(256), 0, stream,
        stgb, 0L, pbuf + 1*SL, PB, pbuf + 1*SL, PB, rst, 0L, pbuf + 2*SL, PB);
    hipLaunchKernelGGL(kpropf, dim3(128,8), dim3(256), 0, stream,
        dyb, DYB, pbuf + 3*SL, PB, pbuf + 3*SL, PB, rdy, 2048L, pbuf + 4*SL, PB);
    hipLaunchKernelGGL(kpropf, dim3(128,8), dim3(256), 0, stream,
        dytb, DYB, pbuf + 5*SL, PB, pbuf + 5*SL, PB, cdy, 2048L, pbuf + 6*SL, PB);
    // combine: xpre = Weff @ feats + bias + residual
    hipLaunchKernelGGL((kprop<1,1>), dim3(128,1,8), dim3(256), 0, stream,
        pbuf, PB, 2048, 224, weff, 0L, 224, pbuf, PB, (const float*)nullptr, 0L, bw, (u16*)nullptr, xpre, 65536L);
    hipLaunchKernelGGL(kstats, dim3(8), dim3(256), 0, stream, xpre, st8);
    hipLaunchKernelGGL(kapply, dim3(32,8), dim3(256), 0, stream,
        xpre, st8, nw + i*65536, nb + i*65536, pbuf, hid);
  }
  hipLaunchKernelGGL(kskip, dim3(256), dim3(256), 0, stream,
      hid, 128, 32, sEW, 32, sEb, skip, 1, 1, xsb);
  hipLaunchKernelGGL(kend, dim3(256), dim3(256), 0, stream, xsb, eW, eb, d_out, flag);
}

// Round 4
// 1002.131 us; speedup vs baseline: 1.1826x; 1.1024x over previous
//
#include <hip/hip_runtime.h>
#include <stdint.h>

// Net_18021682774696 — MTGNN-ish: 3x { TCN(2 gated units) ; skip ; 3x mixprop ; LN+ReLU } + end convs.
// Round 4: fused 3-graph propagation kernels (shared-X for hop1), kcvtT bank-conflict fix.

typedef uint16_t u16;
typedef uint32_t u32;
typedef __attribute__((ext_vector_type(8))) short s8v;
typedef __attribute__((ext_vector_type(4))) float f4v;

#define MFMA16(a,b,c) __builtin_amdgcn_mfma_f32_16x16x32_bf16(a,b,c,0,0,0)

__device__ __forceinline__ float b2f(u16 u){ union{u32 i; float f;} x; x.i=(u32)u<<16; return x.f; }
__device__ __forceinline__ u16 f2b(float f){
  u32 u = __builtin_bit_cast(u32, f);
  u32 r = (u + 0x7fffu + ((u >> 16) & 1u)) >> 16;   // RNE
  return (u16)r;
}

// ---------------------------------------------------------------------------
// kdetect: fp32 (flag=1) vs bf16 (flag=0) input detection.
// ---------------------------------------------------------------------------
__global__ __launch_bounds__(256) void kdetect(const u16* __restrict__ x, int* __restrict__ flag)
{
  const int i = threadIdx.x;
  int cnt = 0;
  for (int k = i; k < 65536; k += 256) {
    const u16 v = x[k];
    if ((v & 0x7F80u) == 0x7F80u) cnt++;
  }
  __shared__ int s[256];
  s[i] = cnt; __syncthreads();
  for (int st = 128; st; st >>= 1) { if (i < st) s[i] += s[i+st]; __syncthreads(); }
  if (i == 0) flag[0] = (s[0] > 0) ? 1 : 0;
}

// kcvt4: canonicalize one array into bf16 (4 elements/thread).
__global__ __launch_bounds__(256) void kcvt4(const void* __restrict__ src, u16* __restrict__ dst,
                                             int n4, const int* __restrict__ flag)
{
  const int i = blockIdx.x*256 + threadIdx.x;
  if (i >= n4) return;
  if (*flag) {
    const float4 v = ((const float4*)src)[i];
    u16 o[4]; o[0]=f2b(v.x); o[1]=f2b(v.y); o[2]=f2b(v.z); o[3]=f2b(v.w);
    *(uint2*)(dst + (long)i*4) = *(uint2*)o;
  } else {
    *(uint2*)(dst + (long)i*4) = ((const uint2*)src)[i];
  }
}

// kcvt_small: all 22 small inputs in one launch.
struct CvtTab { const void* s[22]; u16* d[22]; int n4[22]; };
__global__ __launch_bounds__(256) void kcvt_small(CvtTab tb, const int* __restrict__ flag)
{
  const int e = blockIdx.y;
  const int i = blockIdx.x*256 + threadIdx.x;
  if (i >= tb.n4[e]) return;
  if (*flag) {
    const float4 v = ((const float4*)tb.s[e])[i];
    u16 o[4]; o[0]=f2b(v.x); o[1]=f2b(v.y); o[2]=f2b(v.z); o[3]=f2b(v.w);
    *(uint2*)(tb.d[e] + (long)i*4) = *(uint2*)o;
  } else {
    *(uint2*)(tb.d[e] + (long)i*4) = ((const uint2*)tb.s[e])[i];
  }
}

// ---------------------------------------------------------------------------
// kcvtT: dy -> dyb (bf16) + dytb (bf16 transposed) + row/col sum atomics.
//   64x64 tiles via LDS, stride 66 (bank-stride 33 == 1 mod 32: conflict-free
//   column reads, ~2-way on writes).
// ---------------------------------------------------------------------------
__global__ __launch_bounds__(256) void kcvtT(
    const void* __restrict__ src, u16* __restrict__ dyb, u16* __restrict__ dytb,
    float* __restrict__ rsum, float* __restrict__ csum, const int* __restrict__ flag)
{
  __shared__ u16 t[64][66];
  const int tid = threadIdx.x;
  const int b = blockIdx.z;
  const long r0 = (long)blockIdx.y*64, c0 = (long)blockIdx.x*64;
  const int r = tid>>2, cs16 = (tid&3)*16;
  const long base = (long)b*4194304;
  u16 v16[16];
  if (*flag) {
    const float* sp = (const float*)src + base + (r0+r)*2048 + c0 + cs16;
    #pragma unroll
    for (int q=0; q<4; q++) {
      float4 f = *(const float4*)(sp + q*4);
      v16[q*4+0]=f2b(f.x); v16[q*4+1]=f2b(f.y); v16[q*4+2]=f2b(f.z); v16[q*4+3]=f2b(f.w);
    }
  } else {
    const u16* sp = (const u16*)src + base + (r0+r)*2048 + c0 + cs16;
    *(uint4*)&v16[0] = *(const uint4*)sp;
    *(uint4*)&v16[8] = *(const uint4*)(sp+8);
  }
  *(uint4*)(dyb + base + (r0+r)*2048 + c0 + cs16)     = *(uint4*)&v16[0];
  *(uint4*)(dyb + base + (r0+r)*2048 + c0 + cs16 + 8) = *(uint4*)&v16[8];
  float s = 0.f;
  #pragma unroll
  for (int e=0; e<16; e++) s += b2f(v16[e]);
  #pragma unroll
  for (int q=0; q<8; q++) {
    const u32 w = (u32)v16[2*q] | ((u32)v16[2*q+1] << 16);
    *(u32*)&t[r][cs16 + 2*q] = w;
  }
  s += __shfl_down(s, 2, 64);
  s += __shfl_down(s, 1, 64);
  if ((tid&3)==0) atomicAdd(rsum + b*2048 + r0 + r, s);
  __syncthreads();
  const int c = tid>>2, rs16 = (tid&3)*16;
  u16 w16[16]; float cssum = 0.f;
  #pragma unroll
  for (int e=0; e<16; e++) { w16[e] = t[rs16+e][c]; cssum += b2f(w16[e]); }
  *(uint4*)(dytb + base + (c0+c)*2048 + r0 + rs16)     = *(uint4*)&w16[0];
  *(uint4*)(dytb + base + (c0+c)*2048 + r0 + rs16 + 8) = *(uint4*)&w16[8];
  cssum += __shfl_down(cssum, 2, 64);
  cssum += __shfl_down(cssum, 1, 64);
  if ((tid&3)==0) atomicAdd(csum + b*2048 + c0 + c, cssum);
}

__global__ void kfin(float* __restrict__ v){   // v = 1/(1+v)
  const int i = blockIdx.x*256 + threadIdx.x;
  v[i] = 1.f/(1.f + v[i]);
}

// ---------------------------------------------------------------------------
// kprop3: fused 3-graph propagation hop.
//   For g in {0,1,2}: out_g[v,c] = (sum_k A_g[v,k] X_g[c,k] + X_g[c,v]) * rinv_g[v]
//   (D == X holds for both hops: hop1 h=x, hop2 h=p1_g.)
//   SHAREX=1: X identical for all graphs (hop1) -> X-fragments loaded once.
//   K split across 4 waves (512 each); LDS only for the cross-wave reduction.
// ---------------------------------------------------------------------------
struct P3 {
  const u16* A0; const u16* A1; const u16* A2;
  long ab0, ab1, ab2;
  const u16* X0; const u16* X1; const u16* X2;
  const float* R0; const float* R1; const float* R2;
  long rb0, rb1, rb2;
  u16* O0; u16* O1; u16* O2;
};

template<int SHAREX, int U>
__global__ __launch_bounds__(256, 4) void kprop3(P3 p, long x_bs, long o_bs)
{
  __shared__ f4v red[4][6][64];
  const int tid = threadIdx.x, wave = tid>>6, lane = tid&63;
  const int lw = lane&15, quad = lane>>4;
  const int v0 = blockIdx.x*16;
  const int b  = blockIdx.y;
  const long rowoff = (long)(v0+lw)*2048 + quad*8;
  const u16* Ar[3] = { p.A0 + (long)b*p.ab0 + rowoff,
                       p.A1 + (long)b*p.ab1 + rowoff,
                       p.A2 + (long)b*p.ab2 + rowoff };
  const u16* Xl[3];
  Xl[0] = p.X0 + (long)b*x_bs + quad*8;
  Xl[1] = SHAREX ? Xl[0] : (p.X1 + (long)b*x_bs + quad*8);
  Xl[2] = SHAREX ? Xl[0] : (p.X2 + (long)b*x_bs + quad*8);
  f4v acc[6];
  #pragma unroll
  for (int t = 0; t < 6; t++) acc[t] = (f4v){0.f,0.f,0.f,0.f};
  const int kbase = wave*512;
  #pragma unroll 1
  for (int cc = 0; cc < 16; cc += U) {
    s8v a[3][U], xv[3][2][U];
    #pragma unroll
    for (int u = 0; u < U; u++) {
      const int k = kbase + (cc+u)*32;
      a[0][u] = *(const s8v*)(Ar[0] + k);
      a[1][u] = *(const s8v*)(Ar[1] + k);
      a[2][u] = *(const s8v*)(Ar[2] + k);
      xv[0][0][u] = *(const s8v*)(Xl[0] + (long)lw*2048 + k);
      xv[0][1][u] = *(const s8v*)(Xl[0] + (long)(16+lw)*2048 + k);
      if (!SHAREX) {
        xv[1][0][u] = *(const s8v*)(Xl[1] + (long)lw*2048 + k);
        xv[1][1][u] = *(const s8v*)(Xl[1] + (long)(16+lw)*2048 + k);
        xv[2][0][u] = *(const s8v*)(Xl[2] + (long)lw*2048 + k);
        xv[2][1][u] = *(const s8v*)(Xl[2] + (long)(16+lw)*2048 + k);
      }
    }
    #pragma unroll
    for (int u = 0; u < U; u++) {
      #pragma unroll
      for (int g = 0; g < 3; g++) {
        const int sg = SHAREX ? 0 : g;
        acc[g*2+0] = MFMA16(a[g][u], xv[sg][0][u], acc[g*2+0]);
        acc[g*2+1] = MFMA16(a[g][u], xv[sg][1][u], acc[g*2+1]);
      }
    }
  }
  #pragma unroll
  for (int t = 0; t < 6; t++) red[wave][t][lane] = acc[t];
  __syncthreads();
  if (wave == 0) {
    const int vb = v0 + quad*4;
    #pragma unroll
    for (int t = 0; t < 6; t++) {
      const int g = t >> 1, nt = t & 1;
      f4v s = red[0][t][lane] + red[1][t][lane] + red[2][t][lane] + red[3][t][lane];
      const int c = nt*16 + lw;
      const u16* Xg   = (g==0) ? p.X0 : (g==1) ? (SHAREX ? p.X0 : p.X1) : (SHAREX ? p.X0 : p.X2);
      const float* Rg = (g==0) ? p.R0 : (g==1) ? p.R1 : p.R2;
      const long rbs  = (g==0) ? p.rb0 : (g==1) ? p.rb1 : p.rb2;
      u16* Og         = (g==0) ? p.O0 : (g==1) ? p.O1 : p.O2;
      const u16* dp = Xg + (long)b*x_bs + (long)c*2048 + vb;
      const float* rp = Rg + (long)b*rbs + vb;
      u16 pk[4];
      #pragma unroll
      for (int r = 0; r < 4; r++) pk[r] = f2b((s[r] + b2f(dp[r])) * rp[r]);
      *(uint2*)(Og + (long)b*o_bs + (long)c*2048 + vb) = *(uint2*)pk;
    }
  }
}

// ---------------------------------------------------------------------------
// kprop (LDS-staged, kept for the TRANSA=1 combine pass):
//   MODE 1: out = acc + bias[c] + D[c,v] -> f32
// ---------------------------------------------------------------------------
template<int TRANSA, int MODE>
__global__ __launch_bounds__(256) void kprop(
    const u16* __restrict__ A, long a_bs, int lda, int K,
    const u16* __restrict__ X, long x_bs, int ldx,
    const u16* __restrict__ D, long d_bs,
    const float* __restrict__ rinv, long r_bs,
    const float* __restrict__ bias,
    u16* __restrict__ out0, float* __restrict__ out1, long o_bs)
{
  __shared__ u16 As[4][2][16][40];
  __shared__ f4v red[4][2][64];
  const int tid = threadIdx.x;
  const int wave = tid >> 6, lane = tid & 63;
  const int lw = lane & 15, quad = lane >> 4;
  const int v0 = blockIdx.x * 16;
  const int ball = blockIdx.z + blockIdx.y;
  const u16* Ab = A + (long)ball * a_bs;
  const u16* Xb = X + (long)ball * x_bs;
  const int KC = K >> 5;

  f4v acc0 = {0.f,0.f,0.f,0.f}, acc1 = {0.f,0.f,0.f,0.f};

  int r0, c0_;
  if (TRANSA == 0) { r0 = lane >> 2; c0_ = (lane & 3) * 8; }
  else             { r0 = lane >> 1; c0_ = (lane & 1) * 8; }

  int ci = wave;
  bool has = ci < KC;
  uint4 d = make_uint4(0,0,0,0);
  if (has) {
    d = (TRANSA == 0)
      ? *(const uint4*)(Ab + (long)(v0 + r0) * lda + ci * 32 + c0_)
      : *(const uint4*)(Ab + (long)(ci * 32 + r0) * lda + v0 + c0_);
  }
  int buf = 0;
  while (has) {
    if (TRANSA == 0) {
      *(uint4*)&As[wave][buf][r0][c0_] = d;
    } else {
      u16 tmp[8]; *(uint4*)tmp = d;
      #pragma unroll
      for (int e = 0; e < 8; e++) As[wave][buf][c0_ + e][r0] = tmp[e];
    }
    const int cn = ci + 4;
    const bool hn = cn < KC;
    if (hn) {
      d = (TRANSA == 0)
        ? *(const uint4*)(Ab + (long)(v0 + r0) * lda + cn * 32 + c0_)
        : *(const uint4*)(Ab + (long)(cn * 32 + r0) * lda + v0 + c0_);
    }
    s8v af = *(const s8v*)&As[wave][buf][lw][quad * 8];
    const u16* xk = Xb + ci * 32 + quad * 8;
    s8v b0 = *(const s8v*)(xk + (long)lw * ldx);
    s8v b1 = *(const s8v*)(xk + (long)(16 + lw) * ldx);
    acc0 = MFMA16(af, b0, acc0);
    acc1 = MFMA16(af, b1, acc1);
    ci = cn; has = hn; buf ^= 1;
  }
  red[wave][0][lane] = acc0;
  red[wave][1][lane] = acc1;
  __syncthreads();
  if (wave == 0) {
    const int vb = v0 + quad * 4;
    #pragma unroll
    for (int nt = 0; nt < 2; nt++) {
      f4v a = red[0][nt][lane] + red[1][nt][lane] + red[2][nt][lane] + red[3][nt][lane];
      const int c = nt * 16 + lw;
      const u16* dp = D + (long)ball * d_bs + (long)c * 2048 + vb;
      if (MODE == 0) {
        const float* rp = rinv + (long)ball * r_bs + vb;
        u16 pk[4];
        #pragma unroll
        for (int r = 0; r < 4; r++) pk[r] = f2b((a[r] + b2f(dp[r])) * rp[r]);
        *(uint2*)(out0 + (long)ball * o_bs + (long)c * 2048 + vb) = *(uint2*)pk;
      } else {
        const float bs = bias[c];
        float4 st;
        st.x = a[0] + bs + b2f(dp[0]);
        st.y = a[1] + bs + b2f(dp[1]);
        st.z = a[2] + bs + b2f(dp[2]);
        st.w = a[3] + bs + b2f(dp[3]);
        *(float4*)(out1 + (long)ball * o_bs + (long)c * 2048 + vb) = st;
      }
    }
  }
}

// ---------------------------------------------------------------------------
// ktcn (LDS-free): out[j,o] = tanh(H@Wf^T+bf)*sigmoid(H@Wg^T+bg)
// ---------------------------------------------------------------------------
__global__ __launch_bounds__(256) void ktcn(
    const u16* __restrict__ H, const u16* __restrict__ Wf, const u16* __restrict__ bfv,
    const u16* __restrict__ Wg, const u16* __restrict__ bgv, u16* __restrict__ out)
{
  const int tid = threadIdx.x, wave = tid>>6, lane = tid&63, lw = lane&15, quad = lane>>4;
  const long j0 = (long)blockIdx.x*64 + wave*16;
  const f4v zero = {0.f,0.f,0.f,0.f};
  f4v accf[8], accg[8];
  #pragma unroll
  for (int nt=0; nt<8; nt++){ accf[nt] = zero; accg[nt] = zero; }
  const u16* Arow = H + (j0 + lw)*128 + quad*8;
  #pragma unroll
  for (int k0 = 0; k0 < 128; k0 += 32) {
    s8v a = *(const s8v*)(Arow + k0);
    #pragma unroll
    for (int nt = 0; nt < 8; nt++) {
      const int o = nt*16 + lw;
      s8v bf_ = *(const s8v*)(Wf + o*128 + k0 + quad*8);
      s8v bg_ = *(const s8v*)(Wg + o*128 + k0 + quad*8);
      accf[nt] = MFMA16(a, bf_, accf[nt]);
      accg[nt] = MFMA16(a, bg_, accg[nt]);
    }
  }
  #pragma unroll
  for (int nt = 0; nt < 8; nt++) {
    const int o = nt*16 + lw;
    const float fb = b2f(bfv[o]), gb = b2f(bgv[o]);
    #pragma unroll
    for (int rr = 0; rr < 4; rr++) {
      const long j = j0 + quad*4 + rr;
      const float f = accf[nt][rr] + fb, g = accg[nt][rr] + gb;
      const float e2 = __expf(2.f*f);
      const float th = 1.f - 2.f/(e2 + 1.f);
      const float sg = 1.f/(1.f + __expf(-g));
      out[j*128 + o] = f2b(th*sg);
    }
  }
}

// ---------------------------------------------------------------------------
// kskip (LDS-free): C[j,o] = A@W^T + bias (+ prev skip).  N=256.
// ---------------------------------------------------------------------------
__global__ __launch_bounds__(256) void kskip(
    const u16* __restrict__ A, int lda, int K,
    const u16* __restrict__ W, int ldb,
    const u16* __restrict__ bias,
    float* __restrict__ skipbuf, int addprev, int mode, u16* __restrict__ outb)
{
  const int tid = threadIdx.x, wave = tid>>6, lane = tid&63, lw = lane&15, quad = lane>>4;
  const long j0 = (long)blockIdx.x*64 + wave*16;
  const f4v zero = {0.f,0.f,0.f,0.f};
  f4v acc[16];
  #pragma unroll
  for (int nt=0; nt<16; nt++) acc[nt] = zero;
  const u16* Arow = A + (j0 + lw)*(long)lda + quad*8;
  for (int k0 = 0; k0 < K; k0 += 32) {
    s8v a = *(const s8v*)(Arow + k0);
    #pragma unroll
    for (int nt = 0; nt < 16; nt++) {
      const int o = nt*16 + lw;
      s8v b = *(const s8v*)(W + (long)o*ldb + k0 + quad*8);
      acc[nt] = MFMA16(a, b, acc[nt]);
    }
  }
  #pragma unroll
  for (int nt = 0; nt < 16; nt++) {
    const int o = nt*16 + lw;
    const float bv = b2f(bias[o]);
    #pragma unroll
    for (int rr = 0; rr < 4; rr++) {
      const long j = j0 + quad*4 + rr;
      float v = acc[nt][rr] + bv;
      if (addprev) v += skipbuf[j*256 + o];
      if (mode == 0) skipbuf[j*256 + o] = v;
      else           outb[j*256 + o] = f2b(v);
    }
  }
}

// ---------------------------------------------------------------------------
// kend (LDS-free): out[b,t,n] = xs@endW^T + end_b.  N=12, K=256.
// ---------------------------------------------------------------------------
__global__ __launch_bounds__(256) void kend(
    const u16* __restrict__ A, const u16* __restrict__ W, const u16* __restrict__ bias,
    void* __restrict__ outv, const int* __restrict__ flag)
{
  const int tid = threadIdx.x, wave = tid>>6, lane = tid&63, lw = lane&15, quad = lane>>4;
  const long j0 = (long)blockIdx.x*64 + wave*16;
  f4v acc = {0.f,0.f,0.f,0.f};
  const u16* Arow = A + (j0 + lw)*256 + quad*8;
  #pragma unroll
  for (int k0 = 0; k0 < 256; k0 += 32) {
    s8v a = *(const s8v*)(Arow + k0);
    s8v b = {0,0,0,0,0,0,0,0};
    if (lw < 12) b = *(const s8v*)(W + lw*256 + k0 + quad*8);
    acc = MFMA16(a, b, acc);
  }
  if (lw < 12) {
    const float bv = b2f(bias[lw]);
    const int fl = *flag;
    #pragma unroll
    for (int rr = 0; rr < 4; rr++) {
      const long j = j0 + quad*4 + rr;
      const long oi = (j >> 11)*24576 + lw*2048 + (j & 2047);
      const float val = acc[rr] + bv;
      if (fl) ((float*)outv)[oi] = val;
      else    ((u16*)outv)[oi]   = f2b(val);
    }
  }
}

// --------- small helpers ----------------------------------------------------
__global__ __launch_bounds__(256) void kxcl(const u16* __restrict__ src, u16* __restrict__ hid, int c0)
{
  __shared__ u16 t[32][72];
  const int tid = threadIdx.x, b = blockIdx.y, v0 = blockIdx.x*64;
  const int c = tid>>3, v8 = (tid&7)*8;
  *(uint4*)&t[c][v8] = *(const uint4*)(src + (long)b*65536 + (long)c*2048 + v0 + v8);
  __syncthreads();
  const int jl = tid>>2, c8 = (tid&3)*8;
  u16 q8[8];
  #pragma unroll
  for (int e = 0; e < 8; e++) q8[e] = t[c8 + e][jl];
  *(uint4*)(hid + ((long)b*2048 + v0 + jl)*128 + c0 + c8) = *(uint4*)q8;
}

__global__ void kcopyx(const u16* __restrict__ x, u16* __restrict__ pbuf)
{
  const int tI = blockIdx.x*256 + threadIdx.x;
  const int b = tI >> 13, rr = tI & 8191;
  *(uint4*)(pbuf + (long)b*458752 + rr*8) = *(const uint4*)(x + (long)b*65536 + rr*8);
}

__global__ __launch_bounds__(256) void krowsum(const u16* __restrict__ src, float* __restrict__ outv, int nrows)
{
  const int wave = threadIdx.x>>6, lane = threadIdx.x&63;
  const int row = blockIdx.x*4 + wave;
  if (row >= nrows) return;
  const u16* p = src + (long)row*2048 + lane*8;
  float s = 0.f;
  #pragma unroll
  for (int it = 0; it < 4; it++) {
    u16 v[8]; *(uint4*)v = *(const uint4*)(p + it*512);
    #pragma unroll
    for (int e = 0; e < 8; e++) s += b2f(v[e]);
  }
  #pragma unroll
  for (int off = 32; off; off >>= 1) s += __shfl_down(s, off, 64);
  if (lane == 0) outv[row] = 1.f/(1.f + s);
}

__global__ __launch_bounds__(256) void kweff(
    const u16* __restrict__ g0W, const u16* __restrict__ g1W, const u16* __restrict__ g2W,
    const u16* __restrict__ g0b, const u16* __restrict__ g1b, const u16* __restrict__ g2b,
    int ioff, int boff, u16* __restrict__ weff, float* __restrict__ bw)
{
  const int idx = blockIdx.x*256 + threadIdx.x;
  if (idx < 32) bw[idx] = b2f(g0b[boff+idx]) + b2f(g1b[boff+idx]) + b2f(g2b[boff+idx]);
  if (idx >= 7168) return;
  const int o = idx / 224, m = idx % 224;
  const u16* Ws[3] = {g0W + ioff, g1W + ioff, g2W + ioff};
  float val;
  if (m < 32) {
    val = 0.f;
    #pragma unroll
    for (int g = 0; g < 3; g++) {
      const float w0 = b2f(Ws[g][o*96 + m]);
      const float w1 = b2f(Ws[g][o*96 + 32 + m]);
      const float w2 = b2f(Ws[g][o*96 + 64 + m]);
      val += w0 + 0.05f*(w1 + w2);
    }
  } else {
    const int f = (m - 32) >> 5, cc = m & 31;
    const int g = f >> 1, typ = f & 1;
    const float w1 = b2f(Ws[g][o*96 + 32 + cc]);
    const float w2 = b2f(Ws[g][o*96 + 64 + cc]);
    val = (typ == 0) ? (0.95f*w1 + 0.0475f*w2) : (0.9025f*w2);
  }
  weff[o*224 + m] = f2b(val);
}

__global__ __launch_bounds__(256) void kstats(const float* __restrict__ xpre, float* __restrict__ stats)
{
  const int b = blockIdx.x, tid = threadIdx.x;
  const float4* p = (const float4*)(xpre + (long)b*65536);
  float s = 0.f, q = 0.f;
  for (int i = tid; i < 16384; i += 256) {
    float4 v = p[i];
    s += v.x + v.y + v.z + v.w;
    q += v.x*v.x + v.y*v.y + v.z*v.z + v.w*v.w;
  }
  __shared__ float ss[256], qq[256];
  ss[tid] = s; qq[tid] = q;
  __syncthreads();
  for (int st = 128; st; st >>= 1) {
    if (tid < st) { ss[tid] += ss[tid+st]; qq[tid] += qq[tid+st]; }
    __syncthreads();
  }
  if (tid == 0) {
    const float mu = ss[0] * (1.f/65536.f);
    const float var = qq[0] * (1.f/65536.f) - mu*mu;
    stats[b*2] = mu;
    stats[b*2+1] = rsqrtf(var + 1e-5f);
  }
}

__global__ __launch_bounds__(256) void kapply(
    const float* __restrict__ xpre, const float* __restrict__ stats,
    const u16* __restrict__ nw, const u16* __restrict__ nb,
    u16* __restrict__ slot0, u16* __restrict__ hid)
{
  __shared__ u16 t[32][72];
  const int tid = threadIdx.x, b = blockIdx.y, v0 = blockIdx.x*64;
  const float mu = stats[b*2], rs = stats[b*2+1];
  const int c = tid>>3, v8 = (tid&7)*8;
  const long boff = (long)c*2048 + v0 + v8;
  float4 xa = *(const float4*)(xpre + (long)b*65536 + boff);
  float4 xbv = *(const float4*)(xpre + (long)b*65536 + boff + 4);
  u16 wv[8], bv[8], o8[8];
  *(uint4*)wv = *(const uint4*)(nw + boff);
  *(uint4*)bv = *(const uint4*)(nb + boff);
  const float xs[8] = {xa.x, xa.y, xa.z, xa.w, xbv.x, xbv.y, xbv.z, xbv.w};
  #pragma unroll
  for (int e = 0; e < 8; e++) {
    float y = (xs[e] - mu) * rs * b2f(wv[e]) + b2f(bv[e]);
    y = fmaxf(y, 0.f);
    o8[e] = f2b(y);
    t[c][v8 + e] = o8[e];
  }
  *(uint4*)(slot0 + (long)b*458752 + boff) = *(uint4*)o8;
  __syncthreads();
  const int jl = tid>>2, c8 = (tid&3)*8;
  u16 q8[8];
  #pragma unroll
  for (int e = 0; e < 8; e++) q8[e] = t[c8 + e][jl];
  *(uint4*)(hid + ((long)b*2048 + v0 + jl)*128 + c8) = *(uint4*)q8;
}

// ---------------------------------------------------------------------------
extern "C" void kernel_launch(void* const* d_in, const int* in_sizes, int n_in,
                              void* d_out, int out_size, void* d_ws, size_t ws_size,
                              hipStream_t stream)
{
  (void)in_sizes; (void)n_in; (void)out_size; (void)ws_size;

  char* ws = (char*)d_ws;
  u16*   pbuf = (u16*)(ws + 0);          // [8][7][32][2048] bf16
  u16*   hid  = (u16*)(ws + 7340032);    // [16384][128] bf16
  u16*   hb1  = (u16*)(ws + 11534336);
  u16*   hb2  = (u16*)(ws + 15728640);
  float* skip = (float*)(ws + 19922944); // [16384][256] f32
  u16*   xsb  = (u16*)(ws + 36700160);   // [16384][256] bf16
  float* xpre = (float*)(ws + 45088768); // [8][32][2048] f32
  u16*   weff = (u16*)(ws + 47185920);
  float* bw   = (float*)(ws + 47202304);
  float* rst  = (float*)(ws + 47203328); // [2048]
  float* rdy  = (float*)(ws + 47211520); // [8][2048]  (contiguous with cdy)
  float* cdy  = (float*)(ws + 47277056); // [8][2048]
  float* st8  = (float*)(ws + 47342592);
  int*   flag = (int*)(ws + 47343616);

  size_t coff = 50331648;
  auto alloc = [&](size_t elems) -> u16* {
    u16* p = (u16*)(ws + coff);
    coff += ((elems*2 + 255)/256)*256;
    return p;
  };
  u16* dyb   = alloc(33554432);
  u16* stgb  = alloc(4194304);
  u16* xb    = alloc(524288);
  u16* spatb = alloc(524288);
  u16* tdeb  = alloc(524288);
  u16* tweb  = alloc(524288);
  u16* encWf = alloc(98304);
  u16* encbf = alloc(768);
  u16* encWg = alloc(98304);
  u16* encbg = alloc(768);
  u16* skW   = alloc(98304);
  u16* skb   = alloc(768);
  u16* nw    = alloc(196608);
  u16* nb    = alloc(196608);
  u16* g0W   = alloc(9216);
  u16* g0b   = alloc(96);
  u16* g1W   = alloc(9216);
  u16* g1b   = alloc(96);
  u16* g2W   = alloc(9216);
  u16* g2b   = alloc(96);
  u16* sEW   = alloc(8192);
  u16* sEb   = alloc(256);
  u16* eW    = alloc(3072);
  u16* eb    = alloc(12);
  u16* dytb  = alloc(33554432);

  hipLaunchKernelGGL(kdetect, dim3(1), dim3(256), 0, stream, (const u16*)d_in[0], flag);

  CvtTab tb;
  {
    const void* ss[22] = { d_in[0], d_in[3], d_in[4], d_in[5],
      d_in[6], d_in[7], d_in[8], d_in[9], d_in[10], d_in[11], d_in[12], d_in[13],
      d_in[14], d_in[15], d_in[16], d_in[17], d_in[18], d_in[19], d_in[20], d_in[21],
      d_in[22], d_in[23] };
    u16* dd[22] = { xb, spatb, tdeb, tweb, encWf, encbf, encWg, encbg, skW, skb,
      nw, nb, g0W, g0b, g1W, g1b, g2W, g2b, sEW, sEb, eW, eb };
    const int nn[22] = { 131072, 131072, 131072, 131072, 24576, 192, 24576, 192,
      24576, 192, 49152, 49152, 2304, 24, 2304, 24, 2304, 24, 2048, 64, 768, 3 };
    for (int e = 0; e < 22; e++) { tb.s[e] = ss[e]; tb.d[e] = dd[e]; tb.n4[e] = nn[e]; }
  }
  hipLaunchKernelGGL(kcvt_small, dim3(512, 22), dim3(256), 0, stream, tb, flag);
  hipLaunchKernelGGL(kcvt4, dim3(4096), dim3(256), 0, stream, d_in[2], stgb, 1048576, flag);

  hipMemsetAsync(rdy, 0, 131072, stream);   // zeroes rdy+cdy (contiguous)
  hipLaunchKernelGGL(kcvtT, dim3(32,32,8), dim3(256), 0, stream,
      d_in[1], dyb, dytb, rdy, cdy, flag);
  hipLaunchKernelGGL(kfin, dim3(128), dim3(256), 0, stream, rdy);
  hipLaunchKernelGGL(krowsum, dim3(512), dim3(256), 0, stream, stgb, rst, 2048);

  hipLaunchKernelGGL(kxcl, dim3(32,8), dim3(256), 0, stream, xb,    hid, 0);
  hipLaunchKernelGGL(kxcl, dim3(32,8), dim3(256), 0, stream, spatb, hid, 32);
  hipLaunchKernelGGL(kxcl, dim3(32,8), dim3(256), 0, stream, tdeb,  hid, 64);
  hipLaunchKernelGGL(kxcl, dim3(32,8), dim3(256), 0, stream, tweb,  hid, 96);
  hipLaunchKernelGGL(kcopyx, dim3(256), dim3(256), 0, stream, xb, pbuf);

  const long PB = 458752;
  const long SL = 65536;
  const long DYB = 4194304;

  for (int i = 0; i < 3; i++) {
    hipLaunchKernelGGL(ktcn, dim3(256), dim3(256), 0, stream,
        hid, encWf + (i*2+0)*16384, encbf + (i*2+0)*128, encWg + (i*2+0)*16384, encbg + (i*2+0)*128, hb1);
    hipLaunchKernelGGL(ktcn, dim3(256), dim3(256), 0, stream,
        hb1, encWf + (i*2+1)*16384, encbf + (i*2+1)*128, encWg + (i*2+1)*16384, encbg + (i*2+1)*128, hb2);
    hipLaunchKernelGGL(kskip, dim3(256), dim3(256), 0, stream,
        hb2, 128, 128, skW + i*32768, 128, skb + i*256, skip, (i>0)?1:0, 0, (u16*)nullptr);
    hipLaunchKernelGGL(kweff, dim3(28), dim3(256), 0, stream,
        g0W, g1W, g2W, g0b, g1b, g2b, i*3072, i*32, weff, bw);

    // hop 1: all three graphs fused, shared X (= slot0 = x)
    P3 p1;
    p1.A0 = stgb; p1.A1 = dyb; p1.A2 = dytb;
    p1.ab0 = 0;   p1.ab1 = DYB; p1.ab2 = DYB;
    p1.X0 = pbuf; p1.X1 = pbuf; p1.X2 = pbuf;
    p1.R0 = rst;  p1.R1 = rdy;  p1.R2 = cdy;
    p1.rb0 = 0;   p1.rb1 = 2048; p1.rb2 = 2048;
    p1.O0 = pbuf + 1*SL; p1.O1 = pbuf + 3*SL; p1.O2 = pbuf + 5*SL;
    hipLaunchKernelGGL((kprop3<1,2>), dim3(128,8), dim3(256), 0, stream, p1, PB, PB);

    // hop 2: fused, per-graph X (= p1 slots)
    P3 p2 = p1;
    p2.X0 = pbuf + 1*SL; p2.X1 = pbuf + 3*SL; p2.X2 = pbuf + 5*SL;
    p2.O0 = pbuf + 2*SL; p2.O1 = pbuf + 4*SL; p2.O2 = pbuf + 6*SL;
    hipLaunchKernelGGL((kprop3<0,1>), dim3(128,8), dim3(256), 0, stream, p2, PB, PB);

    // combine: xpre = Weff @ feats + bias + residual
    hipLaunchKernelGGL((kprop<1,1>), dim3(128,1,8), dim3(256), 0, stream,
        pbuf, PB, 2048, 224, weff, 0L, 224, pbuf, PB, (const float*)nullptr, 0L, bw, (u16*)nullptr, xpre, 65536L);
    hipLaunchKernelGGL(kstats, dim3(8), dim3(256), 0, stream, xpre, st8);
    hipLaunchKernelGGL(kapply, dim3(32,8), dim3(256), 0, stream,
        xpre, st8, nw + i*65536, nb + i*65536, pbuf, hid);
  }
  hipLaunchKernelGGL(kskip, dim3(256), dim3(256), 0, stream,
      hid, 128, 32, sEW, 32, sEb, skip, 1, 1, xsb);
  hipLaunchKernelGGL(kend, dim3(256), dim3(256), 0, stream, xsb, eW, eb, d_out, flag);
}

// Round 5
// 893.555 us; speedup vs baseline: 1.3263x; 1.1215x over previous
//
#include <hip/hip_runtime.h>
#include <stdint.h>

// Net_18021682774696 — MTGNN-ish: 3x { TCN(2 gated units) ; skip ; 3x mixprop ; LN+ReLU } + end convs.
// Round 5: uncapped-VGPR register-pipelined kprop3 (spill fix), reworked kcvtT,
// parallelized kdetect/kstats, fused khid0.

typedef uint16_t u16;
typedef uint32_t u32;
typedef __attribute__((ext_vector_type(8))) short s8v;
typedef __attribute__((ext_vector_type(4))) float f4v;

#define MFMA16(a,b,c) __builtin_amdgcn_mfma_f32_16x16x32_bf16(a,b,c,0,0,0)

__device__ __forceinline__ float b2f(u16 u){ union{u32 i; float f;} x; x.i=(u32)u<<16; return x.f; }
__device__ __forceinline__ u16 f2b(float f){
  u32 u = __builtin_bit_cast(u32, f);
  u32 r = (u + 0x7fffu + ((u >> 16) & 1u)) >> 16;   // RNE
  return (u16)r;
}

// ---------------------------------------------------------------------------
// kdetect: fp32 (flag=1) vs bf16 (flag=0), vectorized burst scan of 128 KB.
// ---------------------------------------------------------------------------
__global__ __launch_bounds__(256) void kdetect(const u16* __restrict__ x, int* __restrict__ flag)
{
  const int i = threadIdx.x;
  const uint4* p = (const uint4*)x;   // 65536 u16 = 8192 uint4
  int cnt = 0;
  #pragma unroll
  for (int q = 0; q < 32; q++) {
    const uint4 v = p[i + q*256];
    const u32 w[4] = {v.x, v.y, v.z, v.w};
    #pragma unroll
    for (int e = 0; e < 4; e++) {
      if ((w[e] & 0x7F80u) == 0x7F80u) cnt++;
      if (((w[e] >> 16) & 0x7F80u) == 0x7F80u) cnt++;
    }
  }
  __shared__ int s[256];
  s[i] = cnt; __syncthreads();
  for (int st = 128; st; st >>= 1) { if (i < st) s[i] += s[i+st]; __syncthreads(); }
  if (i == 0) flag[0] = (s[0] > 0) ? 1 : 0;
}

// kcvt4: canonicalize one array into bf16 (4 elements/thread).
__global__ __launch_bounds__(256) void kcvt4(const void* __restrict__ src, u16* __restrict__ dst,
                                             int n4, const int* __restrict__ flag)
{
  const int i = blockIdx.x*256 + threadIdx.x;
  if (i >= n4) return;
  if (*flag) {
    const float4 v = ((const float4*)src)[i];
    u16 o[4]; o[0]=f2b(v.x); o[1]=f2b(v.y); o[2]=f2b(v.z); o[3]=f2b(v.w);
    *(uint2*)(dst + (long)i*4) = *(uint2*)o;
  } else {
    *(uint2*)(dst + (long)i*4) = ((const uint2*)src)[i];
  }
}

// kcvt_small: 18 small weight inputs in one launch.
struct CvtTab { const void* s[18]; u16* d[18]; int n4[18]; };
__global__ __launch_bounds__(256) void kcvt_small(CvtTab tb, const int* __restrict__ flag)
{
  const int e = blockIdx.y;
  const int i = blockIdx.x*256 + threadIdx.x;
  if (i >= tb.n4[e]) return;
  if (*flag) {
    const float4 v = ((const float4*)tb.s[e])[i];
    u16 o[4]; o[0]=f2b(v.x); o[1]=f2b(v.y); o[2]=f2b(v.z); o[3]=f2b(v.w);
    *(uint2*)(tb.d[e] + (long)i*4) = *(uint2*)o;
  } else {
    *(uint2*)(tb.d[e] + (long)i*4) = ((const uint2*)tb.s[e])[i];
  }
}

// ---------------------------------------------------------------------------
// kcvtT: dy -> dyb (bf16) + dytb (bf16 transposed) + row/col sum atomics.
//   Block = 64 rows x 256 cols; 16 float4 burst per lane; transposed LDS store
//   (scalar writes) -> contiguous b128 column reads.
// ---------------------------------------------------------------------------
__global__ __launch_bounds__(256) void kcvtT(
    const void* __restrict__ src, u16* __restrict__ dyb, u16* __restrict__ dytb,
    float* __restrict__ rsum, float* __restrict__ csum, const int* __restrict__ flag)
{
  __shared__ u16 tt[256][72];          // [col-in-block][row], b128-aligned rows
  const int tid = threadIdx.x;
  const int b = blockIdx.z;
  const long r0 = (long)blockIdx.y*64;
  const long c0 = (long)blockIdx.x*256;
  const int r = tid>>2, cg = (tid&3)*16;
  const long base = (long)b*4194304;
  const int fl = *flag;
  float rs = 0.f;
  #pragma unroll
  for (int st = 0; st < 4; st++) {
    const long cc = c0 + st*64 + cg;
    u16 v16[16];
    if (fl) {
      const float* sp = (const float*)src + base + (r0+r)*2048 + cc;
      #pragma unroll
      for (int q = 0; q < 4; q++) {
        const float4 f = ((const float4*)sp)[q];
        v16[q*4+0]=f2b(f.x); v16[q*4+1]=f2b(f.y); v16[q*4+2]=f2b(f.z); v16[q*4+3]=f2b(f.w);
      }
    } else {
      const u16* sp = (const u16*)src + base + (r0+r)*2048 + cc;
      *(uint4*)&v16[0] = ((const uint4*)sp)[0];
      *(uint4*)&v16[8] = ((const uint4*)sp)[1];
    }
    *(uint4*)(dyb + base + (r0+r)*2048 + cc)     = *(uint4*)&v16[0];
    *(uint4*)(dyb + base + (r0+r)*2048 + cc + 8) = *(uint4*)&v16[8];
    #pragma unroll
    for (int e = 0; e < 16; e++) { rs += b2f(v16[e]); tt[st*64 + cg + e][r] = v16[e]; }
  }
  rs += __shfl_down(rs, 2, 64);
  rs += __shfl_down(rs, 1, 64);
  if ((tid&3)==0) atomicAdd(rsum + b*2048 + r0 + r, rs);
  __syncthreads();
  // phase 2: thread = one of 256 columns; contiguous 128B read + write
  u16 col[64];
  #pragma unroll
  for (int q = 0; q < 8; q++) *(uint4*)&col[q*8] = *(const uint4*)&tt[tid][q*8];
  float cs = 0.f;
  #pragma unroll
  for (int e = 0; e < 64; e++) cs += b2f(col[e]);
  u16* dp = dytb + base + (c0 + tid)*2048 + r0;
  #pragma unroll
  for (int q = 0; q < 8; q++) *(uint4*)(dp + q*8) = *(uint4*)&col[q*8];
  atomicAdd(csum + b*2048 + c0 + tid, cs);
}

__global__ void kfin(float* __restrict__ v){   // v = 1/(1+v)
  const int i = blockIdx.x*256 + threadIdx.x;
  v[i] = 1.f/(1.f + v[i]);
}

// ---------------------------------------------------------------------------
// kprop3: fused 3-graph propagation hop, register double-buffered pipeline.
//   out_g[v,c] = (sum_k A_g[v,k] X_g[c,k] + X_g[c,v]) * rinv_g[v]
//   No launch_bounds cap (spill fix). 8 stages of 64 k-elems per wave-chunk;
//   stage s+1 loads issued before stage s MFMAs retire.
// ---------------------------------------------------------------------------
struct P3 {
  const u16* A0; const u16* A1; const u16* A2;
  long ab0, ab1, ab2;
  const u16* X0; const u16* X1; const u16* X2;
  const float* R0; const float* R1; const float* R2;
  long rb0, rb1, rb2;
  u16* O0; u16* O1; u16* O2;
};

template<int SHAREX>
__global__ __launch_bounds__(256) void kprop3(P3 p, long x_bs, long o_bs)
{
  constexpr int NS = SHAREX ? 5 : 9;
  __shared__ f4v red[4][6][64];
  const int tid = threadIdx.x, wave = tid>>6, lane = tid&63;
  const int lw = lane&15, quad = lane>>4;
  const int v0 = blockIdx.x*16;
  const int b = blockIdx.y;
  const long ko = (long)(wave*512 + quad*8);
  const u16* ptr[9];
  ptr[0] = p.A0 + (long)b*p.ab0 + (long)(v0+lw)*2048 + ko;
  ptr[1] = p.A1 + (long)b*p.ab1 + (long)(v0+lw)*2048 + ko;
  ptr[2] = p.A2 + (long)b*p.ab2 + (long)(v0+lw)*2048 + ko;
  ptr[3] = p.X0 + (long)b*x_bs + (long)lw*2048 + ko;
  ptr[4] = p.X0 + (long)b*x_bs + (long)(16+lw)*2048 + ko;
  if (!SHAREX) {
    ptr[5] = p.X1 + (long)b*x_bs + (long)lw*2048 + ko;
    ptr[6] = p.X1 + (long)b*x_bs + (long)(16+lw)*2048 + ko;
    ptr[7] = p.X2 + (long)b*x_bs + (long)lw*2048 + ko;
    ptr[8] = p.X2 + (long)b*x_bs + (long)(16+lw)*2048 + ko;
  }
  f4v acc[6];
  #pragma unroll
  for (int t = 0; t < 6; t++) acc[t] = (f4v){0.f,0.f,0.f,0.f};
  s8v B0[NS][2], B1[NS][2];

  auto LD = [&](s8v (&B)[NS][2], int off){
    #pragma unroll
    for (int s = 0; s < NS; s++) {
      B[s][0] = *(const s8v*)(ptr[s] + off);
      B[s][1] = *(const s8v*)(ptr[s] + off + 32);
    }
  };
  auto FM = [&](s8v (&B)[NS][2]){
    #pragma unroll
    for (int u = 0; u < 2; u++) {
      if (SHAREX) {
        acc[0] = MFMA16(B[0][u], B[3][u], acc[0]);
        acc[1] = MFMA16(B[0][u], B[4][u], acc[1]);
        acc[2] = MFMA16(B[1][u], B[3][u], acc[2]);
        acc[3] = MFMA16(B[1][u], B[4][u], acc[3]);
        acc[4] = MFMA16(B[2][u], B[3][u], acc[4]);
        acc[5] = MFMA16(B[2][u], B[4][u], acc[5]);
      } else {
        acc[0] = MFMA16(B[0][u], B[3][u], acc[0]);
        acc[1] = MFMA16(B[0][u], B[4][u], acc[1]);
        acc[2] = MFMA16(B[1][u], B[5][u], acc[2]);
        acc[3] = MFMA16(B[1][u], B[6][u], acc[3]);
        acc[4] = MFMA16(B[2][u], B[7][u], acc[4]);
        acc[5] = MFMA16(B[2][u], B[8][u], acc[5]);
      }
    }
  };

  LD(B0, 0);                       // stage 0
  #pragma unroll 1
  for (int i = 0; i < 3; i++) {
    LD(B1, 64);                    // stage 2i+1
    FM(B0);                        // stage 2i
    LD(B0, 128);                   // stage 2i+2
    FM(B1);                        // stage 2i+1
    #pragma unroll
    for (int s = 0; s < NS; s++) ptr[s] += 128;
  }
  LD(B1, 64);                      // stage 7
  FM(B0);                          // stage 6
  FM(B1);                          // stage 7

  #pragma unroll
  for (int t = 0; t < 6; t++) red[wave][t][lane] = acc[t];
  __syncthreads();
  if (wave < 3) {
    const int vb = v0 + quad*4;
    const u16* Xg   = (wave==0) ? p.X0 : (wave==1) ? (SHAREX ? p.X0 : p.X1) : (SHAREX ? p.X0 : p.X2);
    const float* Rg = (wave==0) ? p.R0 : (wave==1) ? p.R1 : p.R2;
    const long rbs  = (wave==0) ? p.rb0 : (wave==1) ? p.rb1 : p.rb2;
    u16* Og         = (wave==0) ? p.O0 : (wave==1) ? p.O1 : p.O2;
    #pragma unroll
    for (int nt = 0; nt < 2; nt++) {
      const int t = wave*2 + nt;
      f4v s = red[0][t][lane] + red[1][t][lane] + red[2][t][lane] + red[3][t][lane];
      const int c = nt*16 + lw;
      const u16* dp = Xg + (long)b*x_bs + (long)c*2048 + vb;
      const float* rp = Rg + (long)b*rbs + vb;
      u16 pk[4];
      #pragma unroll
      for (int r = 0; r < 4; r++) pk[r] = f2b((s[r] + b2f(dp[r])) * rp[r]);
      *(uint2*)(Og + (long)b*o_bs + (long)c*2048 + vb) = *(uint2*)pk;
    }
  }
}

// ---------------------------------------------------------------------------
// kprop (LDS-staged, kept for the TRANSA=1 combine pass):
//   MODE 1: out = acc + bias[c] + D[c,v] -> f32
// ---------------------------------------------------------------------------
template<int TRANSA, int MODE>
__global__ __launch_bounds__(256) void kprop(
    const u16* __restrict__ A, long a_bs, int lda, int K,
    const u16* __restrict__ X, long x_bs, int ldx,
    const u16* __restrict__ D, long d_bs,
    const float* __restrict__ rinv, long r_bs,
    const float* __restrict__ bias,
    u16* __restrict__ out0, float* __restrict__ out1, long o_bs)
{
  __shared__ u16 As[4][2][16][40];
  __shared__ f4v red[4][2][64];
  const int tid = threadIdx.x;
  const int wave = tid >> 6, lane = tid & 63;
  const int lw = lane & 15, quad = lane >> 4;
  const int v0 = blockIdx.x * 16;
  const int ball = blockIdx.z + blockIdx.y;
  const u16* Ab = A + (long)ball * a_bs;
  const u16* Xb = X + (long)ball * x_bs;
  const int KC = K >> 5;

  f4v acc0 = {0.f,0.f,0.f,0.f}, acc1 = {0.f,0.f,0.f,0.f};

  int r0, c0_;
  if (TRANSA == 0) { r0 = lane >> 2; c0_ = (lane & 3) * 8; }
  else             { r0 = lane >> 1; c0_ = (lane & 1) * 8; }

  int ci = wave;
  bool has = ci < KC;
  uint4 d = make_uint4(0,0,0,0);
  if (has) {
    d = (TRANSA == 0)
      ? *(const uint4*)(Ab + (long)(v0 + r0) * lda + ci * 32 + c0_)
      : *(const uint4*)(Ab + (long)(ci * 32 + r0) * lda + v0 + c0_);
  }
  int buf = 0;
  while (has) {
    if (TRANSA == 0) {
      *(uint4*)&As[wave][buf][r0][c0_] = d;
    } else {
      u16 tmp[8]; *(uint4*)tmp = d;
      #pragma unroll
      for (int e = 0; e < 8; e++) As[wave][buf][c0_ + e][r0] = tmp[e];
    }
    const int cn = ci + 4;
    const bool hn = cn < KC;
    if (hn) {
      d = (TRANSA == 0)
        ? *(const uint4*)(Ab + (long)(v0 + r0) * lda + cn * 32 + c0_)
        : *(const uint4*)(Ab + (long)(cn * 32 + r0) * lda + v0 + c0_);
    }
    s8v af = *(const s8v*)&As[wave][buf][lw][quad * 8];
    const u16* xk = Xb + ci * 32 + quad * 8;
    s8v b0 = *(const s8v*)(xk + (long)lw * ldx);
    s8v b1 = *(const s8v*)(xk + (long)(16 + lw) * ldx);
    acc0 = MFMA16(af, b0, acc0);
    acc1 = MFMA16(af, b1, acc1);
    ci = cn; has = hn; buf ^= 1;
  }
  red[wave][0][lane] = acc0;
  red[wave][1][lane] = acc1;
  __syncthreads();
  if (wave == 0) {
    const int vb = v0 + quad * 4;
    #pragma unroll
    for (int nt = 0; nt < 2; nt++) {
      f4v a = red[0][nt][lane] + red[1][nt][lane] + red[2][nt][lane] + red[3][nt][lane];
      const int c = nt * 16 + lw;
      const u16* dp = D + (long)ball * d_bs + (long)c * 2048 + vb;
      if (MODE == 0) {
        const float* rp = rinv + (long)ball * r_bs + vb;
        u16 pk[4];
        #pragma unroll
        for (int r = 0; r < 4; r++) pk[r] = f2b((a[r] + b2f(dp[r])) * rp[r]);
        *(uint2*)(out0 + (long)ball * o_bs + (long)c * 2048 + vb) = *(uint2*)pk;
      } else {
        const float bs = bias[c];
        float4 st;
        st.x = a[0] + bs + b2f(dp[0]);
        st.y = a[1] + bs + b2f(dp[1]);
        st.z = a[2] + bs + b2f(dp[2]);
        st.w = a[3] + bs + b2f(dp[3]);
        *(float4*)(out1 + (long)ball * o_bs + (long)c * 2048 + vb) = st;
      }
    }
  }
}

// ---------------------------------------------------------------------------
// ktcn (LDS-free): out[j,o] = tanh(H@Wf^T+bf)*sigmoid(H@Wg^T+bg)
// ---------------------------------------------------------------------------
__global__ __launch_bounds__(256) void ktcn(
    const u16* __restrict__ H, const u16* __restrict__ Wf, const u16* __restrict__ bfv,
    const u16* __restrict__ Wg, const u16* __restrict__ bgv, u16* __restrict__ out)
{
  const int tid = threadIdx.x, wave = tid>>6, lane = tid&63, lw = lane&15, quad = lane>>4;
  const long j0 = (long)blockIdx.x*64 + wave*16;
  const f4v zero = {0.f,0.f,0.f,0.f};
  f4v accf[8], accg[8];
  #pragma unroll
  for (int nt=0; nt<8; nt++){ accf[nt] = zero; accg[nt] = zero; }
  const u16* Arow = H + (j0 + lw)*128 + quad*8;
  #pragma unroll
  for (int k0 = 0; k0 < 128; k0 += 32) {
    s8v a = *(const s8v*)(Arow + k0);
    #pragma unroll
    for (int nt = 0; nt < 8; nt++) {
      const int o = nt*16 + lw;
      s8v bf_ = *(const s8v*)(Wf + o*128 + k0 + quad*8);
      s8v bg_ = *(const s8v*)(Wg + o*128 + k0 + quad*8);
      accf[nt] = MFMA16(a, bf_, accf[nt]);
      accg[nt] = MFMA16(a, bg_, accg[nt]);
    }
  }
  #pragma unroll
  for (int nt = 0; nt < 8; nt++) {
    const int o = nt*16 + lw;
    const float fb = b2f(bfv[o]), gb = b2f(bgv[o]);
    #pragma unroll
    for (int rr = 0; rr < 4; rr++) {
      const long j = j0 + quad*4 + rr;
      const float f = accf[nt][rr] + fb, g = accg[nt][rr] + gb;
      const float e2 = __expf(2.f*f);
      const float th = 1.f - 2.f/(e2 + 1.f);
      const float sg = 1.f/(1.f + __expf(-g));
      out[j*128 + o] = f2b(th*sg);
    }
  }
}

// ---------------------------------------------------------------------------
// kskip (LDS-free): C[j,o] = A@W^T + bias (+ prev skip).  N=256.
// ---------------------------------------------------------------------------
__global__ __launch_bounds__(256) void kskip(
    const u16* __restrict__ A, int lda, int K,
    const u16* __restrict__ W, int ldb,
    const u16* __restrict__ bias,
    float* __restrict__ skipbuf, int addprev, int mode, u16* __restrict__ outb)
{
  const int tid = threadIdx.x, wave = tid>>6, lane = tid&63, lw = lane&15, quad = lane>>4;
  const long j0 = (long)blockIdx.x*64 + wave*16;
  const f4v zero = {0.f,0.f,0.f,0.f};
  f4v acc[16];
  #pragma unroll
  for (int nt=0; nt<16; nt++) acc[nt] = zero;
  const u16* Arow = A + (j0 + lw)*(long)lda + quad*8;
  for (int k0 = 0; k0 < K; k0 += 32) {
    s8v a = *(const s8v*)(Arow + k0);
    #pragma unroll
    for (int nt = 0; nt < 16; nt++) {
      const int o = nt*16 + lw;
      s8v b = *(const s8v*)(W + (long)o*ldb + k0 + quad*8);
      acc[nt] = MFMA16(a, b, acc[nt]);
    }
  }
  #pragma unroll
  for (int nt = 0; nt < 16; nt++) {
    const int o = nt*16 + lw;
    const float bv = b2f(bias[o]);
    #pragma unroll
    for (int rr = 0; rr < 4; rr++) {
      const long j = j0 + quad*4 + rr;
      float v = acc[nt][rr] + bv;
      if (addprev) v += skipbuf[j*256 + o];
      if (mode == 0) skipbuf[j*256 + o] = v;
      else           outb[j*256 + o] = f2b(v);
    }
  }
}

// ---------------------------------------------------------------------------
// kend (LDS-free): out[b,t,n] = xs@endW^T + end_b.  N=12, K=256.
// ---------------------------------------------------------------------------
__global__ __launch_bounds__(256) void kend(
    const u16* __restrict__ A, const u16* __restrict__ W, const u16* __restrict__ bias,
    void* __restrict__ outv, const int* __restrict__ flag)
{
  const int tid = threadIdx.x, wave = tid>>6, lane = tid&63, lw = lane&15, quad = lane>>4;
  const long j0 = (long)blockIdx.x*64 + wave*16;
  f4v acc = {0.f,0.f,0.f,0.f};
  const u16* Arow = A + (j0 + lw)*256 + quad*8;
  #pragma unroll
  for (int k0 = 0; k0 < 256; k0 += 32) {
    s8v a = *(const s8v*)(Arow + k0);
    s8v b = {0,0,0,0,0,0,0,0};
    if (lw < 12) b = *(const s8v*)(W + lw*256 + k0 + quad*8);
    acc = MFMA16(a, b, acc);
  }
  if (lw < 12) {
    const float bv = b2f(bias[lw]);
    const int fl = *flag;
    #pragma unroll
    for (int rr = 0; rr < 4; rr++) {
      const long j = j0 + quad*4 + rr;
      const long oi = (j >> 11)*24576 + lw*2048 + (j & 2047);
      const float val = acc[rr] + bv;
      if (fl) ((float*)outv)[oi] = val;
      else    ((u16*)outv)[oi]   = f2b(val);
    }
  }
}

// ---------------------------------------------------------------------------
// khid0: fused convert+transpose of {x, spat, tde, twe} -> hid (channel-last)
//        and x -> pbuf slot0 (channel-first bf16).
// ---------------------------------------------------------------------------
__global__ __launch_bounds__(256) void khid0(
    const void* __restrict__ x, const void* __restrict__ spat,
    const void* __restrict__ tde, const void* __restrict__ twe,
    u16* __restrict__ hid, u16* __restrict__ slot0, const int* __restrict__ flag)
{
  __shared__ u16 t[32][72];
  const int tid = threadIdx.x, b = blockIdx.y, v0 = blockIdx.x*64;
  const int fl = *flag;
  const void* srcs[4] = {x, spat, tde, twe};
  #pragma unroll
  for (int e = 0; e < 4; e++) {
    const int c = tid>>3, v8 = (tid&7)*8;
    const long boff = (long)c*2048 + v0 + v8;
    u16 o8[8];
    if (fl) {
      const float* sp = (const float*)srcs[e] + (long)b*65536 + boff;
      const float4 a = ((const float4*)sp)[0], bb = ((const float4*)sp)[1];
      o8[0]=f2b(a.x); o8[1]=f2b(a.y); o8[2]=f2b(a.z); o8[3]=f2b(a.w);
      o8[4]=f2b(bb.x); o8[5]=f2b(bb.y); o8[6]=f2b(bb.z); o8[7]=f2b(bb.w);
    } else {
      *(uint4*)o8 = *(const uint4*)((const u16*)srcs[e] + (long)b*65536 + boff);
    }
    if (e == 0) *(uint4*)(slot0 + (long)b*458752 + boff) = *(uint4*)o8;
    *(uint4*)&t[c][v8] = *(uint4*)o8;
    __syncthreads();
    const int jl = tid>>2, c8 = (tid&3)*8;
    u16 q8[8];
    #pragma unroll
    for (int i = 0; i < 8; i++) q8[i] = t[c8 + i][jl];
    *(uint4*)(hid + ((long)b*2048 + v0 + jl)*128 + e*32 + c8) = *(uint4*)q8;
    __syncthreads();
  }
}

__global__ __launch_bounds__(256) void krowsum(const u16* __restrict__ src, float* __restrict__ outv, int nrows)
{
  const int wave = threadIdx.x>>6, lane = threadIdx.x&63;
  const int row = blockIdx.x*4 + wave;
  if (row >= nrows) return;
  const u16* p = src + (long)row*2048 + lane*8;
  float s = 0.f;
  #pragma unroll
  for (int it = 0; it < 4; it++) {
    u16 v[8]; *(uint4*)v = *(const uint4*)(p + it*512);
    #pragma unroll
    for (int e = 0; e < 8; e++) s += b2f(v[e]);
  }
  #pragma unroll
  for (int off = 32; off; off >>= 1) s += __shfl_down(s, off, 64);
  if (lane == 0) outv[row] = 1.f/(1.f + s);
}

__global__ __launch_bounds__(256) void kweff(
    const u16* __restrict__ g0W, const u16* __restrict__ g1W, const u16* __restrict__ g2W,
    const u16* __restrict__ g0b, const u16* __restrict__ g1b, const u16* __restrict__ g2b,
    int ioff, int boff, u16* __restrict__ weff, float* __restrict__ bw)
{
  const int idx = blockIdx.x*256 + threadIdx.x;
  if (idx < 32) bw[idx] = b2f(g0b[boff+idx]) + b2f(g1b[boff+idx]) + b2f(g2b[boff+idx]);
  if (idx >= 7168) return;
  const int o = idx / 224, m = idx % 224;
  const u16* Ws[3] = {g0W + ioff, g1W + ioff, g2W + ioff};
  float val;
  if (m < 32) {
    val = 0.f;
    #pragma unroll
    for (int g = 0; g < 3; g++) {
      const float w0 = b2f(Ws[g][o*96 + m]);
      const float w1 = b2f(Ws[g][o*96 + 32 + m]);
      const float w2 = b2f(Ws[g][o*96 + 64 + m]);
      val += w0 + 0.05f*(w1 + w2);
    }
  } else {
    const int f = (m - 32) >> 5, cc = m & 31;
    const int g = f >> 1, typ = f & 1;
    const float w1 = b2f(Ws[g][o*96 + 32 + cc]);
    const float w2 = b2f(Ws[g][o*96 + 64 + cc]);
    val = (typ == 0) ? (0.95f*w1 + 0.0475f*w2) : (0.9025f*w2);
  }
  weff[o*224 + m] = f2b(val);
}

// kstats: per-batch partial (sum, sumsq) over 8192-elem segment -> atomics.
__global__ __launch_bounds__(256) void kstats(const float* __restrict__ xpre, float* __restrict__ raw)
{
  const int b = blockIdx.y, tid = threadIdx.x;
  const float4* p = (const float4*)(xpre + (long)b*65536 + (long)blockIdx.x*8192);
  float s = 0.f, q = 0.f;
  #pragma unroll
  for (int i = 0; i < 8; i++) {
    const float4 v = p[tid + i*256];
    s += v.x + v.y + v.z + v.w;
    q += v.x*v.x + v.y*v.y + v.z*v.z + v.w*v.w;
  }
  __shared__ float ss[256], qq[256];
  ss[tid] = s; qq[tid] = q;
  __syncthreads();
  for (int st = 128; st; st >>= 1) {
    if (tid < st) { ss[tid] += ss[tid+st]; qq[tid] += qq[tid+st]; }
    __syncthreads();
  }
  if (tid == 0) { atomicAdd(raw + b*2, ss[0]); atomicAdd(raw + b*2 + 1, qq[0]); }
}

__global__ __launch_bounds__(256) void kapply(
    const float* __restrict__ xpre, const float* __restrict__ raw,
    const u16* __restrict__ nw, const u16* __restrict__ nb,
    u16* __restrict__ slot0, u16* __restrict__ hid)
{
  __shared__ u16 t[32][72];
  const int tid = threadIdx.x, b = blockIdx.y, v0 = blockIdx.x*64;
  const float mu = raw[b*2] * (1.f/65536.f);
  const float var = raw[b*2+1] * (1.f/65536.f) - mu*mu;
  const float rs = rsqrtf(var + 1e-5f);
  const int c = tid>>3, v8 = (tid&7)*8;
  const long boff = (long)c*2048 + v0 + v8;
  float4 xa = *(const float4*)(xpre + (long)b*65536 + boff);
  float4 xbv = *(const float4*)(xpre + (long)b*65536 + boff + 4);
  u16 wv[8], bv[8], o8[8];
  *(uint4*)wv = *(const uint4*)(nw + boff);
  *(uint4*)bv = *(const uint4*)(nb + boff);
  const float xs[8] = {xa.x, xa.y, xa.z, xa.w, xbv.x, xbv.y, xbv.z, xbv.w};
  #pragma unroll
  for (int e = 0; e < 8; e++) {
    float y = (xs[e] - mu) * rs * b2f(wv[e]) + b2f(bv[e]);
    y = fmaxf(y, 0.f);
    o8[e] = f2b(y);
    t[c][v8 + e] = o8[e];
  }
  *(uint4*)(slot0 + (long)b*458752 + boff) = *(uint4*)o8;
  __syncthreads();
  const int jl = tid>>2, c8 = (tid&3)*8;
  u16 q8[8];
  #pragma unroll
  for (int e = 0; e < 8; e++) q8[e] = t[c8 + e][jl];
  *(uint4*)(hid + ((long)b*2048 + v0 + jl)*128 + c8) = *(uint4*)q8;
}

// ---------------------------------------------------------------------------
extern "C" void kernel_launch(void* const* d_in, const int* in_sizes, int n_in,
                              void* d_out, int out_size, void* d_ws, size_t ws_size,
                              hipStream_t stream)
{
  (void)in_sizes; (void)n_in; (void)out_size; (void)ws_size;

  char* ws = (char*)d_ws;
  u16*   pbuf = (u16*)(ws + 0);          // [8][7][32][2048] bf16
  u16*   hid  = (u16*)(ws + 7340032);    // [16384][128] bf16
  u16*   hb1  = (u16*)(ws + 11534336);
  u16*   hb2  = (u16*)(ws + 15728640);
  float* skip = (float*)(ws + 19922944); // [16384][256] f32
  u16*   xsb  = (u16*)(ws + 36700160);   // [16384][256] bf16
  float* xpre = (float*)(ws + 45088768); // [8][32][2048] f32
  u16*   weff = (u16*)(ws + 47185920);
  float* bw   = (float*)(ws + 47202304);
  float* rst  = (float*)(ws + 47203328); // [2048]
  float* rdy  = (float*)(ws + 47211520); // [8][2048]  (contiguous with cdy)
  float* cdy  = (float*)(ws + 47277056); // [8][2048]
  int*   flag = (int*)(ws + 47343616);
  float* raw  = (float*)(ws + 47343744); // [3][16] LN partials

  size_t coff = 50331648;
  auto alloc = [&](size_t elems) -> u16* {
    u16* p = (u16*)(ws + coff);
    coff += ((elems*2 + 255)/256)*256;
    return p;
  };
  u16* dyb   = alloc(33554432);
  u16* stgb  = alloc(4194304);
  u16* encWf = alloc(98304);
  u16* encbf = alloc(768);
  u16* encWg = alloc(98304);
  u16* encbg = alloc(768);
  u16* skW   = alloc(98304);
  u16* skb   = alloc(768);
  u16* nw    = alloc(196608);
  u16* nb    = alloc(196608);
  u16* g0W   = alloc(9216);
  u16* g0b   = alloc(96);
  u16* g1W   = alloc(9216);
  u16* g1b   = alloc(96);
  u16* g2W   = alloc(9216);
  u16* g2b   = alloc(96);
  u16* sEW   = alloc(8192);
  u16* sEb   = alloc(256);
  u16* eW    = alloc(3072);
  u16* eb    = alloc(12);
  u16* dytb  = alloc(33554432);

  hipLaunchKernelGGL(kdetect, dim3(1), dim3(256), 0, stream, (const u16*)d_in[0], flag);

  CvtTab tb;
  {
    const void* ss[18] = { d_in[6], d_in[7], d_in[8], d_in[9], d_in[10], d_in[11],
      d_in[12], d_in[13], d_in[14], d_in[15], d_in[16], d_in[17], d_in[18], d_in[19],
      d_in[20], d_in[21], d_in[22], d_in[23] };
    u16* dd[18] = { encWf, encbf, encWg, encbg, skW, skb, nw, nb,
      g0W, g0b, g1W, g1b, g2W, g2b, sEW, sEb, eW, eb };
    const int nn[18] = { 24576, 192, 24576, 192, 24576, 192, 49152, 49152,
      2304, 24, 2304, 24, 2304, 24, 2048, 64, 768, 3 };
    for (int e = 0; e < 18; e++) { tb.s[e] = ss[e]; tb.d[e] = dd[e]; tb.n4[e] = nn[e]; }
  }
  hipLaunchKernelGGL(kcvt_small, dim3(192, 18), dim3(256), 0, stream, tb, flag);
  hipLaunchKernelGGL(kcvt4, dim3(4096), dim3(256), 0, stream, d_in[2], stgb, 1048576, flag);

  hipMemsetAsync(rdy, 0, 131072, stream);   // zeroes rdy+cdy (contiguous)
  hipMemsetAsync(raw, 0, 192, stream);
  hipLaunchKernelGGL(kcvtT, dim3(8,32,8), dim3(256), 0, stream,
      d_in[1], dyb, dytb, rdy, cdy, flag);
  hipLaunchKernelGGL(kfin, dim3(128), dim3(256), 0, stream, rdy);
  hipLaunchKernelGGL(krowsum, dim3(512), dim3(256), 0, stream, stgb, rst, 2048);
  hipLaunchKernelGGL(khid0, dim3(32,8), dim3(256), 0, stream,
      d_in[0], d_in[3], d_in[4], d_in[5], hid, pbuf, flag);

  const long PB = 458752;
  const long SL = 65536;
  const long DYB = 4194304;

  for (int i = 0; i < 3; i++) {
    hipLaunchKernelGGL(ktcn, dim3(256), dim3(256), 0, stream,
        hid, encWf + (i*2+0)*16384, encbf + (i*2+0)*128, encWg + (i*2+0)*16384, encbg + (i*2+0)*128, hb1);
    hipLaunchKernelGGL(ktcn, dim3(256), dim3(256), 0, stream,
        hb1, encWf + (i*2+1)*16384, encbf + (i*2+1)*128, encWg + (i*2+1)*16384, encbg + (i*2+1)*128, hb2);
    hipLaunchKernelGGL(kskip, dim3(256), dim3(256), 0, stream,
        hb2, 128, 128, skW + i*32768, 128, skb + i*256, skip, (i>0)?1:0, 0, (u16*)nullptr);
    hipLaunchKernelGGL(kweff, dim3(28), dim3(256), 0, stream,
        g0W, g1W, g2W, g0b, g1b, g2b, i*3072, i*32, weff, bw);

    P3 p1;
    p1.A0 = stgb; p1.A1 = dyb; p1.A2 = dytb;
    p1.ab0 = 0;   p1.ab1 = DYB; p1.ab2 = DYB;
    p1.X0 = pbuf; p1.X1 = pbuf; p1.X2 = pbuf;
    p1.R0 = rst;  p1.R1 = rdy;  p1.R2 = cdy;
    p1.rb0 = 0;   p1.rb1 = 2048; p1.rb2 = 2048;
    p1.O0 = pbuf + 1*SL; p1.O1 = pbuf + 3*SL; p1.O2 = pbuf + 5*SL;
    hipLaunchKernelGGL((kprop3<1>), dim3(128,8), dim3(256), 0, stream, p1, PB, PB);

    P3 p2 = p1;
    p2.X0 = pbuf + 1*SL; p2.X1 = pbuf + 3*SL; p2.X2 = pbuf + 5*SL;
    p2.O0 = pbuf + 2*SL; p2.O1 = pbuf + 4*SL; p2.O2 = pbuf + 6*SL;
    hipLaunchKernelGGL((kprop3<0>), dim3(128,8), dim3(256), 0, stream, p2, PB, PB);

    hipLaunchKernelGGL((kprop<1,1>), dim3(128,1,8), dim3(256), 0, stream,
        pbuf, PB, 2048, 224, weff, 0L, 224, pbuf, PB, (const float*)nullptr, 0L, bw, (u16*)nullptr, xpre, 65536L);
    hipLaunchKernelGGL(kstats, dim3(8,8), dim3(256), 0, stream, xpre, raw + i*16);
    hipLaunchKernelGGL(kapply, dim3(32,8), dim3(256), 0, stream,
        xpre, raw + i*16, nw + i*65536, nb + i*65536, pbuf, hid);
  }
  hipLaunchKernelGGL(kskip, dim3(256), dim3(256), 0, stream,
      hid, 128, 32, sEW, 32, sEb, skip, 1, 1, xsb);
  hipLaunchKernelGGL(kend, dim3(256), dim3(256), 0, stream, xsb, eW, eb, d_out, flag);
}